// Round 1
// baseline (1796.419 us; speedup 1.0000x reference)
//
#include <hip/hip_runtime.h>
#include <hip/hip_bf16.h>
#include <math.h>

// Problem constants
#define S_LEN 2048
#define BATCH 4
#define HID   1024
#define HEADS 16
#define HD    64
#define SB    (S_LEN*BATCH)       // 8192 rows
#define CHUNK 64
#define NCHUNK (S_LEN/CHUNK)      // 32
#define BH    (BATCH*HEADS)       // 64

// ---------------------------------------------------------------------------
// GEMM: Y[M,N] = X[M,K] @ W[N,K]^T + bias, optional activation.
// ACT=0: none. ACT=1: elu(x)+1 = (x>0 ? x+1 : exp(x)).
// 128x128 block tile, BK=16, 256 threads, 8x8 per thread.
// Assumes M%128==0, N%128==0, K%16==0 (true here: 8192,1024,1024).
// ---------------------------------------------------------------------------
template<int ACT>
__global__ __launch_bounds__(256) void gemm_bias_act(
    const float* __restrict__ X, const float* __restrict__ W,
    const float* __restrict__ bias, float* __restrict__ Y,
    int M, int N, int K)
{
    __shared__ float Xs[128][17];
    __shared__ float Ws[128][17];
    const int tid = threadIdx.x;
    const int tx = tid & 15, ty = tid >> 4;
    const int rowBase = blockIdx.y * 128;
    const int colBase = blockIdx.x * 128;

    float acc[8][8] = {};

    const int lr = tid >> 1;          // 0..127
    const int lk = (tid & 1) * 8;     // 0 or 8

    for (int k0 = 0; k0 < K; k0 += 16) {
        const float* xp = X + (size_t)(rowBase + lr) * K + k0 + lk;
        float4 xa = *(const float4*)xp;
        float4 xb = *(const float4*)(xp + 4);
        Xs[lr][lk+0]=xa.x; Xs[lr][lk+1]=xa.y; Xs[lr][lk+2]=xa.z; Xs[lr][lk+3]=xa.w;
        Xs[lr][lk+4]=xb.x; Xs[lr][lk+5]=xb.y; Xs[lr][lk+6]=xb.z; Xs[lr][lk+7]=xb.w;

        const float* wp = W + (size_t)(colBase + lr) * K + k0 + lk;
        float4 wa = *(const float4*)wp;
        float4 wb = *(const float4*)(wp + 4);
        Ws[lr][lk+0]=wa.x; Ws[lr][lk+1]=wa.y; Ws[lr][lk+2]=wa.z; Ws[lr][lk+3]=wa.w;
        Ws[lr][lk+4]=wb.x; Ws[lr][lk+5]=wb.y; Ws[lr][lk+6]=wb.z; Ws[lr][lk+7]=wb.w;

        __syncthreads();
        #pragma unroll
        for (int kk = 0; kk < 16; ++kk) {
            float a[8], b[8];
            #pragma unroll
            for (int i = 0; i < 8; ++i) a[i] = Xs[ty*8+i][kk];
            #pragma unroll
            for (int j = 0; j < 8; ++j) b[j] = Ws[tx*8+j][kk];
            #pragma unroll
            for (int i = 0; i < 8; ++i)
                #pragma unroll
                for (int j = 0; j < 8; ++j)
                    acc[i][j] += a[i]*b[j];
        }
        __syncthreads();
    }

    // epilogue
    #pragma unroll
    for (int i = 0; i < 8; ++i) {
        const int r = rowBase + ty*8 + i;
        const int c0 = colBase + tx*8;
        float v[8];
        #pragma unroll
        for (int j = 0; j < 8; ++j) {
            float val = acc[i][j] + bias[c0 + j];
            if (ACT == 1) val = (val > 0.f) ? (val + 1.f) : __expf(val);
            v[j] = val;
        }
        float4* yp = (float4*)(Y + (size_t)r * N + c0);
        yp[0] = make_float4(v[0], v[1], v[2], v[3]);
        yp[1] = make_float4(v[4], v[5], v[6], v[7]);
    }
}

// ---------------------------------------------------------------------------
// Forget-gate: f = sigmoid(X @ Wf^T + bf) -> f_out (d_out slot 2), logf -> ws
// One block per row (t*B+b). 256 threads; 4 waves handle 16 output heads.
// ---------------------------------------------------------------------------
__global__ __launch_bounds__(256) void fgate_kernel(
    const float* __restrict__ X, const float* __restrict__ Wf,
    const float* __restrict__ bf,
    float* __restrict__ f_out, float* __restrict__ logf_out)
{
    __shared__ float xs[HID];
    const int r = blockIdx.x;
    const int tid = threadIdx.x;

    ((float4*)xs)[tid] = ((const float4*)(X + (size_t)r * HID))[tid];
    __syncthreads();

    const int wave = tid >> 6, lane = tid & 63;
    for (int n = wave; n < HEADS; n += 4) {
        const float* w = Wf + n * HID;
        float s = 0.f;
        for (int kk = lane; kk < HID; kk += 64) s += xs[kk] * w[kk];
        #pragma unroll
        for (int off = 32; off > 0; off >>= 1) s += __shfl_down(s, off);
        if (lane == 0) {
            s += bf[n];
            float fv = 1.f / (1.f + __expf(-s));
            f_out[(size_t)r * HEADS + n]    = fv;
            logf_out[(size_t)r * HEADS + n] = __logf(fv);
        }
    }
}

// ---------------------------------------------------------------------------
// Pass 1: per (bh, chunk) compute chunk-local contributions:
//   Sc[d][e] = sum_j exp(c_63 - c_j) * k[j][d] * v[j][e]
//   zc[d]    = sum_j exp(c_63 - c_j) * k[j][d]
//   D        = exp(c_63)
// where c_j = in-chunk inclusive cumsum of log f.
// ---------------------------------------------------------------------------
__global__ __launch_bounds__(256) void pass1_kernel(
    const float* __restrict__ Kp, const float* __restrict__ Vp,
    const float* __restrict__ logf,
    float* __restrict__ Schunk, float* __restrict__ zchunk,
    float* __restrict__ Dchunk)
{
    const int chunk = blockIdx.x;
    const int bh = blockIdx.y;
    const int b = bh >> 4, h = bh & 15;
    const int tid = threadIdx.x;

    __shared__ float ks[64][65], vs[64][65];
    __shared__ float c[64];

    if (tid < 64)
        c[tid] = logf[(size_t)((chunk*64 + tid)*BATCH + b) * HEADS + h];
    __syncthreads();
    if (tid == 0) { float s = 0.f; for (int j = 0; j < 64; ++j) { s += c[j]; c[j] = s; } }

    for (int idx = tid; idx < 4096; idx += 256) {
        const int j = idx >> 6, d = idx & 63;
        const size_t off = (size_t)((chunk*64 + j)*BATCH + b) * HID + h*HD + d;
        ks[j][d] = Kp[off];
        vs[j][d] = Vp[off];
    }
    __syncthreads();

    const float ctot = c[63];
    const int d = tid >> 2, eg = (tid & 3) << 4;
    float acc[16] = {};
    float zacc = 0.f;
    for (int j = 0; j < 64; ++j) {
        const float w = __expf(ctot - c[j]) * ks[j][d];
        zacc += w;
        #pragma unroll
        for (int i = 0; i < 16; ++i) acc[i] += w * vs[j][eg + i];
    }

    const size_t slot = (size_t)bh * NCHUNK + chunk;
    float* sp = Schunk + slot * 4096;
    #pragma unroll
    for (int i = 0; i < 16; ++i) sp[d*64 + eg + i] = acc[i];
    if (eg == 0) zchunk[slot * 64 + d] = zacc;
    if (tid == 0) Dchunk[slot] = __expf(ctot);
}

// ---------------------------------------------------------------------------
// Pass 2: sequential over chunks per (bh). In-place: Schunk/zchunk slots are
// replaced by the state ENTERING that chunk (S0/z0).
// ---------------------------------------------------------------------------
__global__ __launch_bounds__(256) void pass2_kernel(
    float* __restrict__ Schunk, float* __restrict__ zchunk,
    const float* __restrict__ Dchunk)
{
    const int bh = blockIdx.x;
    const int tid = threadIdx.x;

    float Sprev[16];
    #pragma unroll
    for (int i = 0; i < 16; ++i) Sprev[i] = 0.f;
    float zprev = 0.f;

    const size_t base  = (size_t)bh * NCHUNK * 4096;
    const size_t zbase = (size_t)bh * NCHUNK * 64;

    for (int c = 0; c < NCHUNK; ++c) {
        const float D = Dchunk[bh * NCHUNK + c];
        float* sp = Schunk + base + (size_t)c * 4096;
        float contrib[16];
        #pragma unroll
        for (int i = 0; i < 16; ++i) contrib[i] = sp[i*256 + tid];
        #pragma unroll
        for (int i = 0; i < 16; ++i) {
            sp[i*256 + tid] = Sprev[i];
            Sprev[i] = D * Sprev[i] + contrib[i];
        }
        if (tid < 64) {
            float* zp = zchunk + zbase + (size_t)c * 64;
            const float zc = zp[tid];
            zp[tid] = zprev;
            zprev = D * zprev + zc;
        }
    }
}

// ---------------------------------------------------------------------------
// Pass 3: per (bh, chunk) compute the attention outputs.
//   A[t][j] = (q_t . k_j) * exp(c_t - c_j)   (j <= t)
//   num[t][e] = sum_j A[t][j] v[j][e] + exp(c_t) * sum_d q[t][d] S0[d][e]
//   den[t]    = sum_j A[t][j]         + exp(c_t) * (q_t . z0) + 1e-6
//   out = num/den, written IN-PLACE into the Q buffer.
// ---------------------------------------------------------------------------
__global__ __launch_bounds__(256) void pass3_kernel(
    float* __restrict__ Qp, const float* __restrict__ Kp,
    const float* __restrict__ Vp, const float* __restrict__ logf,
    const float* __restrict__ S0, const float* __restrict__ z0)
{
    const int chunk = blockIdx.x;
    const int bh = blockIdx.y;
    const int b = bh >> 4, h = bh & 15;
    const int tid = threadIdx.x;

    __shared__ float qs[64][65], ks[64][65], vs[64][65], ss[64][65], As[64][65];
    __shared__ float cc[64], zz[64], den[64];

    if (tid < 64)
        cc[tid] = logf[(size_t)((chunk*64 + tid)*BATCH + b) * HEADS + h];
    __syncthreads();
    if (tid == 0) { float s = 0.f; for (int j = 0; j < 64; ++j) { s += cc[j]; cc[j] = s; } }

    const size_t slot = (size_t)bh * NCHUNK + chunk;
    if (tid < 64) zz[tid] = z0[slot * 64 + tid];

    for (int idx = tid; idx < 4096; idx += 256) {
        const int j = idx >> 6, d = idx & 63;
        const size_t off = (size_t)((chunk*64 + j)*BATCH + b) * HID + h*HD + d;
        qs[j][d] = Qp[off];
        ks[j][d] = Kp[off];
        vs[j][d] = Vp[off];
        ss[j][d] = S0[slot * 4096 + idx];  // [state_d][e]
    }
    __syncthreads();

    // Stage 1: scores
    const int t = tid >> 2, jg = (tid & 3) << 4;
    #pragma unroll
    for (int jj = 0; jj < 16; ++jj) {
        const int j = jg + jj;
        float a = 0.f;
        if (j <= t) {
            float dot = 0.f;
            #pragma unroll
            for (int d = 0; d < 64; ++d) dot += qs[t][d] * ks[j][d];
            a = dot * __expf(cc[t] - cc[j]);
        }
        As[t][j] = a;
    }
    __syncthreads();

    // denominators (one thread per t)
    if (tid < 64) {
        float s = 0.f;
        for (int j = 0; j < 64; ++j) s += As[tid][j];
        float qz = 0.f;
        for (int d = 0; d < 64; ++d) qz += qs[tid][d] * zz[d];
        den[tid] = s + __expf(cc[tid]) * qz + 1e-6f;
    }
    __syncthreads();

    // Stage 2: outputs
    const int eg = jg;
    float acc[16] = {};
    for (int j = 0; j < 64; ++j) {
        const float a = As[t][j];
        #pragma unroll
        for (int i = 0; i < 16; ++i) acc[i] += a * vs[j][eg + i];
    }
    float acc2[16] = {};
    for (int d = 0; d < 64; ++d) {
        const float q = qs[t][d];
        #pragma unroll
        for (int i = 0; i < 16; ++i) acc2[i] += q * ss[d][eg + i];
    }
    const float ect = __expf(cc[t]);
    const float invden = 1.f / den[t];
    float* outp = Qp + (size_t)((chunk*64 + t)*BATCH + b) * HID + h*HD + eg;
    #pragma unroll
    for (int i = 0; i < 16; ++i) outp[i] = (acc[i] + ect * acc2[i]) * invden;
}

// ---------------------------------------------------------------------------
extern "C" void kernel_launch(void* const* d_in, const int* in_sizes, int n_in,
                              void* d_out, int out_size, void* d_ws, size_t ws_size,
                              hipStream_t stream) {
    const float* X  = (const float*)d_in[0];
    const float* Wq = (const float*)d_in[1];
    const float* bq = (const float*)d_in[2];
    const float* Wk = (const float*)d_in[3];
    const float* bk = (const float*)d_in[4];
    const float* Wv = (const float*)d_in[5];
    const float* bv = (const float*)d_in[6];
    const float* Wf = (const float*)d_in[7];
    const float* bf = (const float*)d_in[8];
    const float* Wo = (const float*)d_in[9];
    const float* bo = (const float*)d_in[10];

    float* out = (float*)d_out;
    const size_t OUT_SLOT = (size_t)SB * HID;          // 8,388,608

    float* ws = (float*)d_ws;
    float* wsQ    = ws;                                 // 8.4M (becomes attn_out)
    float* wsK    = wsQ + (size_t)SB * HID;             // 8.4M
    float* wsV    = wsK + (size_t)SB * HID;             // 8.4M
    float* wsLogf = wsV + (size_t)SB * HID;             // 131K
    float* wsS    = wsLogf + (size_t)SB * HEADS;        // 8.4M (Schunk -> S0)
    float* wsZ    = wsS + (size_t)BH * NCHUNK * HD*HD;  // 131K (zchunk -> z0)
    float* wsD    = wsZ + (size_t)BH * NCHUNK * HD;     // 2K

    // zeros output (slot 1)
    hipMemsetAsync(out + OUT_SLOT, 0, OUT_SLOT * sizeof(float), stream);

    dim3 ggrid(HID/128, SB/128);
    gemm_bias_act<1><<<ggrid, 256, 0, stream>>>(X, Wq, bq, wsQ, SB, HID, HID);
    gemm_bias_act<1><<<ggrid, 256, 0, stream>>>(X, Wk, bk, wsK, SB, HID, HID);
    gemm_bias_act<0><<<ggrid, 256, 0, stream>>>(X, Wv, bv, wsV, SB, HID, HID);

    fgate_kernel<<<SB, 256, 0, stream>>>(X, Wf, bf, out + 2*OUT_SLOT, wsLogf);

    dim3 sgrid(NCHUNK, BH);
    pass1_kernel<<<sgrid, 256, 0, stream>>>(wsK, wsV, wsLogf, wsS, wsZ, wsD);
    pass2_kernel<<<BH, 256, 0, stream>>>(wsS, wsZ, wsD);
    pass3_kernel<<<sgrid, 256, 0, stream>>>(wsQ, wsK, wsV, wsLogf, wsS, wsZ);

    gemm_bias_act<0><<<ggrid, 256, 0, stream>>>(wsQ, Wo, bo, out, SB, HID, HID);
}

// Round 2
// 610.611 us; speedup vs baseline: 2.9420x; 2.9420x over previous
//
#include <hip/hip_runtime.h>
#include <hip/hip_bf16.h>
#include <math.h>

// Problem constants
#define S_LEN 2048
#define BATCH 4
#define HID   1024
#define HEADS 16
#define HD    64
#define SB    (S_LEN*BATCH)       // 8192 rows
#define CHUNK 64
#define NCHUNK (S_LEN/CHUNK)      // 32
#define BH    (BATCH*HEADS)       // 64

typedef __bf16 bf16x8 __attribute__((ext_vector_type(8)));
typedef float  f32x4  __attribute__((ext_vector_type(4)));
typedef unsigned short ushort_t;

__device__ __forceinline__ unsigned short f2bf(float x) {
    union { float f; unsigned int u; } un; un.f = x;
    unsigned int u = un.u;
    unsigned int r = (u + 0x7FFFu + ((u >> 16) & 1u)) >> 16;  // RNE
    return (unsigned short)r;
}
__device__ __forceinline__ float bf2f(unsigned short s) {
    union { unsigned int u; float f; } un; un.u = ((unsigned int)s) << 16;
    return un.f;
}

// ---------------------------------------------------------------------------
// fp32 -> bf16 convert (vectorized float4 -> 4x bf16)
// ---------------------------------------------------------------------------
__global__ __launch_bounds__(256) void cvt_f32_bf16(
    const float* __restrict__ s, ushort_t* __restrict__ d, int n4)
{
    int i = blockIdx.x * 256 + threadIdx.x;
    if (i < n4) {
        float4 v = ((const float4*)s)[i];
        ushort4 o;
        o.x = f2bf(v.x); o.y = f2bf(v.y); o.z = f2bf(v.z); o.w = f2bf(v.w);
        ((ushort4*)d)[i] = o;
    }
}

// ---------------------------------------------------------------------------
// bf16 MFMA GEMM: Y[M,N] = X[M,K] @ W[N,K]^T + bias (+activation).
// ACT=0 none, ACT=1 elu+1. OBF=1 -> Y is bf16, OBF=0 -> Y is fp32.
// 128x128 block tile, BK=32, 256 threads (4 waves, 2x2 of 64x64 each),
// mfma_f32_16x16x32_bf16, global_load_lds width-16 staging (m97 structure).
// Requires M%128==0, N%128==0, K%32==0.
// ---------------------------------------------------------------------------
template<int ACT, int OBF>
__global__ __launch_bounds__(256) void gemm_mfma(
    const ushort_t* __restrict__ X, const ushort_t* __restrict__ W,
    const float* __restrict__ bias, void* __restrict__ Yv,
    int M, int N, int K)
{
    __shared__ ushort_t As[128 * 32];   // [row][k], unpadded (global_load_lds)
    __shared__ ushort_t Bs[128 * 32];

    const int tid  = threadIdx.x;
    const int wave = tid >> 6, lane = tid & 63;
    const int waveM = wave >> 1, waveN = wave & 1;
    const int rowBase = blockIdx.y * 128;
    const int colBase = blockIdx.x * 128;

    f32x4 acc[4][4];
    #pragma unroll
    for (int i = 0; i < 4; ++i)
        #pragma unroll
        for (int j = 0; j < 4; ++j)
            acc[i][j] = (f32x4){0.f, 0.f, 0.f, 0.f};

    // staging: wave w, issue i covers rows [i*64 + w*16, +16); lane l ->
    // row += l>>2, k-offset (l&3)*8 elements (16B). LDS offset == lane*16. 
    const int srow = lane >> 2;
    const int scol = (lane & 3) * 8;

    const ushort_t* gA0 = X + (size_t)(rowBase + wave*16 + srow) * K + scol;
    const ushort_t* gB0 = W + (size_t)(colBase + wave*16 + srow) * K + scol;
    ushort_t* lA = As + (wave*16)*32;
    ushort_t* lB = Bs + (wave*16)*32;

    const int fr = lane & 15;          // fragment row/col
    const int fk = (lane >> 4) * 8;    // fragment k-offset

    for (int k0 = 0; k0 < K; k0 += 32) {
        __builtin_amdgcn_global_load_lds(
            (const __attribute__((address_space(1))) void*)(gA0 + k0),
            (__attribute__((address_space(3))) void*)lA, 16, 0, 0);
        __builtin_amdgcn_global_load_lds(
            (const __attribute__((address_space(1))) void*)(gA0 + (size_t)64*K + k0),
            (__attribute__((address_space(3))) void*)(lA + 64*32), 16, 0, 0);
        __builtin_amdgcn_global_load_lds(
            (const __attribute__((address_space(1))) void*)(gB0 + k0),
            (__attribute__((address_space(3))) void*)lB, 16, 0, 0);
        __builtin_amdgcn_global_load_lds(
            (const __attribute__((address_space(1))) void*)(gB0 + (size_t)64*K + k0),
            (__attribute__((address_space(3))) void*)(lB + 64*32), 16, 0, 0);

        __syncthreads();   // drains vmcnt, then barrier

        bf16x8 a[4], b[4];
        #pragma unroll
        for (int i = 0; i < 4; ++i)
            a[i] = *(const bf16x8*)(As + (waveM*64 + i*16 + fr)*32 + fk);
        #pragma unroll
        for (int j = 0; j < 4; ++j)
            b[j] = *(const bf16x8*)(Bs + (waveN*64 + j*16 + fr)*32 + fk);

        #pragma unroll
        for (int i = 0; i < 4; ++i)
            #pragma unroll
            for (int j = 0; j < 4; ++j)
                acc[i][j] = __builtin_amdgcn_mfma_f32_16x16x32_bf16(
                    a[i], b[j], acc[i][j], 0, 0, 0);

        __syncthreads();
    }

    // Epilogue. C/D layout: col = lane&15, row = (lane>>4)*4 + reg.
    const int er = (lane >> 4) * 4;
    const int ec = lane & 15;
    #pragma unroll
    for (int i = 0; i < 4; ++i) {
        #pragma unroll
        for (int j = 0; j < 4; ++j) {
            const int r0 = rowBase + waveM*64 + i*16 + er;
            const int c  = colBase + waveN*64 + j*16 + ec;
            const float bv = bias[c];
            #pragma unroll
            for (int k = 0; k < 4; ++k) {
                float v = acc[i][j][k] + bv;
                if (ACT == 1) v = (v > 0.f) ? (v + 1.f) : __expf(v);
                if (OBF)
                    ((ushort_t*)Yv)[(size_t)(r0 + k) * N + c] = f2bf(v);
                else
                    ((float*)Yv)[(size_t)(r0 + k) * N + c] = v;
            }
        }
    }
}

// ---------------------------------------------------------------------------
// Forget-gate: f = sigmoid(X @ Wf^T + bf) -> f_out (fp32, d_out slot 2),
// log f -> ws. Fully fp32 (f is a returned tensor).
// ---------------------------------------------------------------------------
__global__ __launch_bounds__(256) void fgate_kernel(
    const float* __restrict__ X, const float* __restrict__ Wf,
    const float* __restrict__ bf,
    float* __restrict__ f_out, float* __restrict__ logf_out)
{
    __shared__ float xs[HID];
    const int r = blockIdx.x;
    const int tid = threadIdx.x;

    ((float4*)xs)[tid] = ((const float4*)(X + (size_t)r * HID))[tid];
    __syncthreads();

    const int wave = tid >> 6, lane = tid & 63;
    for (int n = wave; n < HEADS; n += 4) {
        const float* w = Wf + n * HID;
        float s = 0.f;
        for (int kk = lane; kk < HID; kk += 64) s += xs[kk] * w[kk];
        #pragma unroll
        for (int off = 32; off > 0; off >>= 1) s += __shfl_down(s, off);
        if (lane == 0) {
            s += bf[n];
            float fv = 1.f / (1.f + __expf(-s));
            f_out[(size_t)r * HEADS + n]    = fv;
            logf_out[(size_t)r * HEADS + n] = __logf(fv);
        }
    }
}

// ---------------------------------------------------------------------------
// Pass 1: per (bh, chunk): chunk-local state contribution.
//   Sc[d][e] = sum_j exp(c_63 - c_j) k[j][d] v[j][e];  zc[d] likewise; D=exp(c_63)
// ---------------------------------------------------------------------------
__global__ __launch_bounds__(256) void pass1_kernel(
    const ushort_t* __restrict__ Kp, const ushort_t* __restrict__ Vp,
    const float* __restrict__ logf,
    float* __restrict__ Schunk, float* __restrict__ zchunk,
    float* __restrict__ Dchunk)
{
    const int chunk = blockIdx.x;
    const int bh = blockIdx.y;
    const int b = bh >> 4, h = bh & 15;
    const int tid = threadIdx.x;

    __shared__ float ks[64][65], vs[64][65];
    __shared__ float c[64];

    if (tid < 64)
        c[tid] = logf[(size_t)((chunk*64 + tid)*BATCH + b) * HEADS + h];
    __syncthreads();
    if (tid == 0) { float s = 0.f; for (int j = 0; j < 64; ++j) { s += c[j]; c[j] = s; } }

    for (int idx = tid; idx < 4096; idx += 256) {
        const int j = idx >> 6, d = idx & 63;
        const size_t off = (size_t)((chunk*64 + j)*BATCH + b) * HID + h*HD + d;
        ks[j][d] = bf2f(Kp[off]);
        vs[j][d] = bf2f(Vp[off]);
    }
    __syncthreads();

    const float ctot = c[63];
    const int d = tid >> 2, eg = (tid & 3) << 4;
    float acc[16] = {};
    float zacc = 0.f;
    for (int j = 0; j < 64; ++j) {
        const float w = __expf(ctot - c[j]) * ks[j][d];
        zacc += w;
        #pragma unroll
        for (int i = 0; i < 16; ++i) acc[i] += w * vs[j][eg + i];
    }

    const size_t slot = (size_t)bh * NCHUNK + chunk;
    float* sp = Schunk + slot * 4096;
    #pragma unroll
    for (int i = 0; i < 16; ++i) sp[d*64 + eg + i] = acc[i];
    if (eg == 0) zchunk[slot * 64 + d] = zacc;
    if (tid == 0) Dchunk[slot] = __expf(ctot);
}

// ---------------------------------------------------------------------------
// Pass 2: sequential over 32 chunks per (bh); in-place replace chunk
// contributions with the state ENTERING the chunk.
// ---------------------------------------------------------------------------
__global__ __launch_bounds__(256) void pass2_kernel(
    float* __restrict__ Schunk, float* __restrict__ zchunk,
    const float* __restrict__ Dchunk)
{
    const int bh = blockIdx.x;
    const int tid = threadIdx.x;

    float Sprev[16];
    #pragma unroll
    for (int i = 0; i < 16; ++i) Sprev[i] = 0.f;
    float zprev = 0.f;

    const size_t base  = (size_t)bh * NCHUNK * 4096;
    const size_t zbase = (size_t)bh * NCHUNK * 64;

    for (int c = 0; c < NCHUNK; ++c) {
        const float D = Dchunk[bh * NCHUNK + c];
        float* sp = Schunk + base + (size_t)c * 4096;
        float contrib[16];
        #pragma unroll
        for (int i = 0; i < 16; ++i) contrib[i] = sp[i*256 + tid];
        #pragma unroll
        for (int i = 0; i < 16; ++i) {
            sp[i*256 + tid] = Sprev[i];
            Sprev[i] = D * Sprev[i] + contrib[i];
        }
        if (tid < 64) {
            float* zp = zchunk + zbase + (size_t)c * 64;
            const float zc = zp[tid];
            zp[tid] = zprev;
            zprev = D * zprev + zc;
        }
    }
}

// ---------------------------------------------------------------------------
// Pass 3: per (bh, chunk) attention outputs, written as bf16 into AO.
// ---------------------------------------------------------------------------
__global__ __launch_bounds__(256) void pass3_kernel(
    const ushort_t* __restrict__ Qp, const ushort_t* __restrict__ Kp,
    const ushort_t* __restrict__ Vp, const float* __restrict__ logf,
    const float* __restrict__ S0, const float* __restrict__ z0,
    ushort_t* __restrict__ AO)
{
    const int chunk = blockIdx.x;
    const int bh = blockIdx.y;
    const int b = bh >> 4, h = bh & 15;
    const int tid = threadIdx.x;

    __shared__ float qs[64][65], ks[64][65], vs[64][65], ss[64][65], As[64][65];
    __shared__ float cc[64], zz[64], den[64];

    if (tid < 64)
        cc[tid] = logf[(size_t)((chunk*64 + tid)*BATCH + b) * HEADS + h];
    __syncthreads();
    if (tid == 0) { float s = 0.f; for (int j = 0; j < 64; ++j) { s += cc[j]; cc[j] = s; } }

    const size_t slot = (size_t)bh * NCHUNK + chunk;
    if (tid < 64) zz[tid] = z0[slot * 64 + tid];

    for (int idx = tid; idx < 4096; idx += 256) {
        const int j = idx >> 6, d = idx & 63;
        const size_t off = (size_t)((chunk*64 + j)*BATCH + b) * HID + h*HD + d;
        qs[j][d] = bf2f(Qp[off]);
        ks[j][d] = bf2f(Kp[off]);
        vs[j][d] = bf2f(Vp[off]);
        ss[j][d] = S0[slot * 4096 + idx];  // [state_d][e]
    }
    __syncthreads();

    // Stage 1: causal decayed scores
    const int t = tid >> 2, jg = (tid & 3) << 4;
    #pragma unroll
    for (int jj = 0; jj < 16; ++jj) {
        const int j = jg + jj;
        float a = 0.f;
        if (j <= t) {
            float dot = 0.f;
            #pragma unroll
            for (int d = 0; d < 64; ++d) dot += qs[t][d] * ks[j][d];
            a = dot * __expf(cc[t] - cc[j]);
        }
        As[t][j] = a;
    }
    __syncthreads();

    if (tid < 64) {
        float s = 0.f;
        for (int j = 0; j < 64; ++j) s += As[tid][j];
        float qz = 0.f;
        for (int d = 0; d < 64; ++d) qz += qs[tid][d] * zz[d];
        den[tid] = s + __expf(cc[tid]) * qz + 1e-6f;
    }
    __syncthreads();

    // Stage 2: outputs
    const int eg = jg;
    float acc[16] = {};
    for (int j = 0; j < 64; ++j) {
        const float a = As[t][j];
        #pragma unroll
        for (int i = 0; i < 16; ++i) acc[i] += a * vs[j][eg + i];
    }
    float acc2[16] = {};
    for (int d = 0; d < 64; ++d) {
        const float q = qs[t][d];
        #pragma unroll
        for (int i = 0; i < 16; ++i) acc2[i] += q * ss[d][eg + i];
    }
    const float ect = __expf(cc[t]);
    const float invden = 1.f / den[t];
    ushort_t* outp = AO + (size_t)((chunk*64 + t)*BATCH + b) * HID + h*HD + eg;
    #pragma unroll
    for (int i = 0; i < 16; ++i) outp[i] = f2bf((acc[i] + ect * acc2[i]) * invden);
}

// ---------------------------------------------------------------------------
extern "C" void kernel_launch(void* const* d_in, const int* in_sizes, int n_in,
                              void* d_out, int out_size, void* d_ws, size_t ws_size,
                              hipStream_t stream) {
    const float* X  = (const float*)d_in[0];
    const float* Wq = (const float*)d_in[1];
    const float* bq = (const float*)d_in[2];
    const float* Wk = (const float*)d_in[3];
    const float* bk = (const float*)d_in[4];
    const float* Wv = (const float*)d_in[5];
    const float* bv = (const float*)d_in[6];
    const float* Wf = (const float*)d_in[7];
    const float* bf = (const float*)d_in[8];
    const float* Wo = (const float*)d_in[9];
    const float* bo = (const float*)d_in[10];

    float* out = (float*)d_out;
    const size_t OUT_SLOT = (size_t)SB * HID;          // 8,388,608

    // Workspace layout (bf16 buffers as ushort)
    char* ws = (char*)d_ws;
    ushort_t* wsXb = (ushort_t*)ws;                         // SB*HID bf16 (X, later attn_out)
    ushort_t* wsWqb = wsXb + (size_t)SB * HID;              // HID*HID bf16 each
    ushort_t* wsWkb = wsWqb + (size_t)HID * HID;
    ushort_t* wsWvb = wsWkb + (size_t)HID * HID;
    ushort_t* wsWob = wsWvb + (size_t)HID * HID;
    ushort_t* wsQ   = wsWob + (size_t)HID * HID;            // SB*HID bf16 each
    ushort_t* wsK   = wsQ + (size_t)SB * HID;
    ushort_t* wsV   = wsK + (size_t)SB * HID;
    float* wsLogf = (float*)(wsV + (size_t)SB * HID);       // SB*HEADS fp32
    float* wsS    = wsLogf + (size_t)SB * HEADS;            // BH*NCHUNK*4096 fp32
    float* wsZ    = wsS + (size_t)BH * NCHUNK * HD * HD;    // BH*NCHUNK*64 fp32
    float* wsD    = wsZ + (size_t)BH * NCHUNK * HD;         // BH*NCHUNK fp32

    // zeros output (slot 1)
    hipMemsetAsync(out + OUT_SLOT, 0, OUT_SLOT * sizeof(float), stream);

    // fp32 -> bf16 converts
    cvt_f32_bf16<<<(SB*HID/4 + 255)/256, 256, 0, stream>>>(X,  wsXb,  SB*HID/4);
    cvt_f32_bf16<<<(HID*HID/4 + 255)/256, 256, 0, stream>>>(Wq, wsWqb, HID*HID/4);
    cvt_f32_bf16<<<(HID*HID/4 + 255)/256, 256, 0, stream>>>(Wk, wsWkb, HID*HID/4);
    cvt_f32_bf16<<<(HID*HID/4 + 255)/256, 256, 0, stream>>>(Wv, wsWvb, HID*HID/4);
    cvt_f32_bf16<<<(HID*HID/4 + 255)/256, 256, 0, stream>>>(Wo, wsWob, HID*HID/4);

    dim3 ggrid(HID/128, SB/128);
    gemm_mfma<1,1><<<ggrid, 256, 0, stream>>>(wsXb, wsWqb, bq, wsQ, SB, HID, HID);
    gemm_mfma<1,1><<<ggrid, 256, 0, stream>>>(wsXb, wsWkb, bk, wsK, SB, HID, HID);
    gemm_mfma<0,1><<<ggrid, 256, 0, stream>>>(wsXb, wsWvb, bv, wsV, SB, HID, HID);

    fgate_kernel<<<SB, 256, 0, stream>>>(X, Wf, bf, out + 2*OUT_SLOT, wsLogf);

    dim3 sgrid(NCHUNK, BH);
    pass1_kernel<<<sgrid, 256, 0, stream>>>(wsK, wsV, wsLogf, wsS, wsZ, wsD);
    pass2_kernel<<<BH, 256, 0, stream>>>(wsS, wsZ, wsD);
    // attn_out (bf16) overwrites wsXb — X bf16 is no longer needed
    pass3_kernel<<<sgrid, 256, 0, stream>>>(wsQ, wsK, wsV, wsLogf, wsS, wsZ, wsXb);

    gemm_mfma<0,0><<<ggrid, 256, 0, stream>>>(wsXb, wsWob, bo, out, SB, HID, HID);
}

// Round 3
// 521.030 us; speedup vs baseline: 3.4478x; 1.1719x over previous
//
#include <hip/hip_runtime.h>
#include <hip/hip_bf16.h>
#include <math.h>

// Problem constants
#define S_LEN 2048
#define BATCH 4
#define HID   1024
#define HEADS 16
#define HD    64
#define SB    (S_LEN*BATCH)       // 8192 rows
#define CHUNK 64
#define NCHUNK (S_LEN/CHUNK)      // 32
#define BH    (BATCH*HEADS)       // 64

typedef __bf16 bf16x8 __attribute__((ext_vector_type(8)));
typedef float  f32x4  __attribute__((ext_vector_type(4)));
typedef unsigned short ushort_t;
typedef unsigned short u16x8 __attribute__((ext_vector_type(8)));

__device__ __forceinline__ unsigned short f2bf(float x) {
    union { float f; unsigned int u; } un; un.f = x;
    unsigned int u = un.u;
    unsigned int r = (u + 0x7FFFu + ((u >> 16) & 1u)) >> 16;  // RNE
    return (unsigned short)r;
}
__device__ __forceinline__ float bf2f(unsigned short s) {
    union { unsigned int u; float f; } un; un.u = ((unsigned int)s) << 16;
    return un.f;
}

// ---------------------------------------------------------------------------
// fp32 -> bf16 convert (vectorized float4 -> 4x bf16)
// ---------------------------------------------------------------------------
__global__ __launch_bounds__(256) void cvt_f32_bf16(
    const float* __restrict__ s, ushort_t* __restrict__ d, int n4)
{
    int i = blockIdx.x * 256 + threadIdx.x;
    if (i < n4) {
        float4 v = ((const float4*)s)[i];
        ushort4 o;
        o.x = f2bf(v.x); o.y = f2bf(v.y); o.z = f2bf(v.z); o.w = f2bf(v.w);
        ((ushort4*)d)[i] = o;
    }
}

// ---------------------------------------------------------------------------
// bf16 MFMA GEMM: Y[M,N] = X[M,K] @ W[N,K]^T + bias (+activation).
// ACT=0 none, ACT=1 elu+1. OBF=1 -> Y is bf16, OBF=0 -> Y is fp32.
// 128x128 block tile, BK=32, 256 threads, mfma_f32_16x16x32_bf16,
// global_load_lds width-16 staging (m97 structure).
// ---------------------------------------------------------------------------
template<int ACT, int OBF>
__global__ __launch_bounds__(256) void gemm_mfma(
    const ushort_t* __restrict__ X, const ushort_t* __restrict__ W,
    const float* __restrict__ bias, void* __restrict__ Yv,
    int M, int N, int K)
{
    __shared__ ushort_t As[128 * 32];
    __shared__ ushort_t Bs[128 * 32];

    const int tid  = threadIdx.x;
    const int wave = tid >> 6, lane = tid & 63;
    const int waveM = wave >> 1, waveN = wave & 1;
    const int rowBase = blockIdx.y * 128;
    const int colBase = blockIdx.x * 128;

    f32x4 acc[4][4];
    #pragma unroll
    for (int i = 0; i < 4; ++i)
        #pragma unroll
        for (int j = 0; j < 4; ++j)
            acc[i][j] = (f32x4){0.f, 0.f, 0.f, 0.f};

    const int srow = lane >> 2;
    const int scol = (lane & 3) * 8;

    const ushort_t* gA0 = X + (size_t)(rowBase + wave*16 + srow) * K + scol;
    const ushort_t* gB0 = W + (size_t)(colBase + wave*16 + srow) * K + scol;
    ushort_t* lA = As + (wave*16)*32;
    ushort_t* lB = Bs + (wave*16)*32;

    const int fr = lane & 15;
    const int fk = (lane >> 4) * 8;

    for (int k0 = 0; k0 < K; k0 += 32) {
        __builtin_amdgcn_global_load_lds(
            (const __attribute__((address_space(1))) void*)(gA0 + k0),
            (__attribute__((address_space(3))) void*)lA, 16, 0, 0);
        __builtin_amdgcn_global_load_lds(
            (const __attribute__((address_space(1))) void*)(gA0 + (size_t)64*K + k0),
            (__attribute__((address_space(3))) void*)(lA + 64*32), 16, 0, 0);
        __builtin_amdgcn_global_load_lds(
            (const __attribute__((address_space(1))) void*)(gB0 + k0),
            (__attribute__((address_space(3))) void*)lB, 16, 0, 0);
        __builtin_amdgcn_global_load_lds(
            (const __attribute__((address_space(1))) void*)(gB0 + (size_t)64*K + k0),
            (__attribute__((address_space(3))) void*)(lB + 64*32), 16, 0, 0);

        __syncthreads();

        bf16x8 a[4], b[4];
        #pragma unroll
        for (int i = 0; i < 4; ++i)
            a[i] = *(const bf16x8*)(As + (waveM*64 + i*16 + fr)*32 + fk);
        #pragma unroll
        for (int j = 0; j < 4; ++j)
            b[j] = *(const bf16x8*)(Bs + (waveN*64 + j*16 + fr)*32 + fk);

        #pragma unroll
        for (int i = 0; i < 4; ++i)
            #pragma unroll
            for (int j = 0; j < 4; ++j)
                acc[i][j] = __builtin_amdgcn_mfma_f32_16x16x32_bf16(
                    a[i], b[j], acc[i][j], 0, 0, 0);

        __syncthreads();
    }

    const int er = (lane >> 4) * 4;
    const int ec = lane & 15;
    #pragma unroll
    for (int i = 0; i < 4; ++i) {
        #pragma unroll
        for (int j = 0; j < 4; ++j) {
            const int r0 = rowBase + waveM*64 + i*16 + er;
            const int c  = colBase + waveN*64 + j*16 + ec;
            const float bv = bias[c];
            #pragma unroll
            for (int k = 0; k < 4; ++k) {
                float v = acc[i][j][k] + bv;
                if (ACT == 1) v = (v > 0.f) ? (v + 1.f) : __expf(v);
                if (OBF)
                    ((ushort_t*)Yv)[(size_t)(r0 + k) * N + c] = f2bf(v);
                else
                    ((float*)Yv)[(size_t)(r0 + k) * N + c] = v;
            }
        }
    }
}

// ---------------------------------------------------------------------------
// Forget-gate: f = sigmoid(X @ Wf^T + bf) -> f_out (fp32), log f -> ws.
// ---------------------------------------------------------------------------
__global__ __launch_bounds__(256) void fgate_kernel(
    const float* __restrict__ X, const float* __restrict__ Wf,
    const float* __restrict__ bf,
    float* __restrict__ f_out, float* __restrict__ logf_out)
{
    __shared__ float xs[HID];
    const int r = blockIdx.x;
    const int tid = threadIdx.x;

    ((float4*)xs)[tid] = ((const float4*)(X + (size_t)r * HID))[tid];
    __syncthreads();

    const int wave = tid >> 6, lane = tid & 63;
    for (int n = wave; n < HEADS; n += 4) {
        const float* w = Wf + n * HID;
        float s = 0.f;
        for (int kk = lane; kk < HID; kk += 64) s += xs[kk] * w[kk];
        #pragma unroll
        for (int off = 32; off > 0; off >>= 1) s += __shfl_down(s, off);
        if (lane == 0) {
            s += bf[n];
            float fv = 1.f / (1.f + __expf(-s));
            f_out[(size_t)r * HEADS + n]    = fv;
            logf_out[(size_t)r * HEADS + n] = __logf(fv);
        }
    }
}

// ---------------------------------------------------------------------------
// Pass 1: per (bh, chunk): chunk-local state contribution.
//   Sc[d][e] = sum_j exp(c_63 - c_j) k[j][d] v[j][e];  zc[d] likewise; D=exp(c_63)
// expf hoisted into shared exd[] (computed once by 64 threads).
// ---------------------------------------------------------------------------
__global__ __launch_bounds__(256) void pass1_kernel(
    const ushort_t* __restrict__ Kp, const ushort_t* __restrict__ Vp,
    const float* __restrict__ logf,
    float* __restrict__ Schunk, float* __restrict__ zchunk,
    float* __restrict__ Dchunk)
{
    const int chunk = blockIdx.x;
    const int bh = blockIdx.y;
    const int b = bh >> 4, h = bh & 15;
    const int tid = threadIdx.x;

    __shared__ float ks[64][65], vs[64][65];
    __shared__ float c[64], exd[64];

    if (tid < 64)
        c[tid] = logf[(size_t)((chunk*64 + tid)*BATCH + b) * HEADS + h];
    __syncthreads();
    if (tid == 0) { float s = 0.f; for (int j = 0; j < 64; ++j) { s += c[j]; c[j] = s; } }

    for (int idx = tid; idx < 4096; idx += 256) {
        const int j = idx >> 6, d = idx & 63;
        const size_t off = (size_t)((chunk*64 + j)*BATCH + b) * HID + h*HD + d;
        ks[j][d] = bf2f(Kp[off]);
        vs[j][d] = bf2f(Vp[off]);
    }
    __syncthreads();
    if (tid < 64) exd[tid] = __expf(c[63] - c[tid]);
    __syncthreads();

    const int d = tid >> 2, eg = (tid & 3) << 4;
    float acc[16] = {};
    float zacc = 0.f;
    for (int j = 0; j < 64; ++j) {
        const float w = exd[j] * ks[j][d];
        zacc += w;
        #pragma unroll
        for (int i = 0; i < 16; ++i) acc[i] += w * vs[j][eg + i];
    }

    const size_t slot = (size_t)bh * NCHUNK + chunk;
    float* sp = Schunk + slot * 4096;
    #pragma unroll
    for (int i = 0; i < 16; ++i) sp[d*64 + eg + i] = acc[i];
    if (eg == 0) zchunk[slot * 64 + d] = zacc;
    if (tid == 0) Dchunk[slot] = __expf(c[63]);
}

// ---------------------------------------------------------------------------
// Pass 2: sequential over 32 chunks per (bh); in-place replace chunk
// contributions with the state ENTERING the chunk.
// ---------------------------------------------------------------------------
__global__ __launch_bounds__(256) void pass2_kernel(
    float* __restrict__ Schunk, float* __restrict__ zchunk,
    const float* __restrict__ Dchunk)
{
    const int bh = blockIdx.x;
    const int tid = threadIdx.x;

    float Sprev[16];
    #pragma unroll
    for (int i = 0; i < 16; ++i) Sprev[i] = 0.f;
    float zprev = 0.f;

    const size_t base  = (size_t)bh * NCHUNK * 4096;
    const size_t zbase = (size_t)bh * NCHUNK * 64;

    for (int c = 0; c < NCHUNK; ++c) {
        const float D = Dchunk[bh * NCHUNK + c];
        float* sp = Schunk + base + (size_t)c * 4096;
        float contrib[16];
        #pragma unroll
        for (int i = 0; i < 16; ++i) contrib[i] = sp[i*256 + tid];
        #pragma unroll
        for (int i = 0; i < 16; ++i) {
            sp[i*256 + tid] = Sprev[i];
            Sprev[i] = D * Sprev[i] + contrib[i];
        }
        if (tid < 64) {
            float* zp = zchunk + zbase + (size_t)c * 64;
            const float zc = zp[tid];
            zp[tid] = zprev;
            zprev = D * zprev + zc;
        }
    }
}

// ---------------------------------------------------------------------------
// Pass 3 (MFMA rewrite): per (bh, chunk) attention outputs -> bf16 AO.
//   Phase A: QK^T via mfma_16x16x32_bf16 (q,k bf16 in LDS, K-major).
//   Phase B: decay+mask in C-layout regs -> P (f32) to LDS; V staged f32
//            (aliases dead K region); den via row-sum + q.z0.
//   Phase C: out[t][e] = (sum_j P[t][j] v[j][e] + e^{c_t} sum_d q[t][d] S0[d][e])/den
// LDS: qs(9216) + [ks(9216) U vs(17408)] + ps(17408) + 1KB = 45056 B -> 3 blk/CU.
// ---------------------------------------------------------------------------
__global__ __launch_bounds__(256) void pass3_kernel(
    const ushort_t* __restrict__ Qp, const ushort_t* __restrict__ Kp,
    const ushort_t* __restrict__ Vp, const float* __restrict__ logf,
    const float* __restrict__ S0, const float* __restrict__ z0,
    ushort_t* __restrict__ AO)
{
    __shared__ __align__(16) char smem[45056];
    ushort_t* qs = (ushort_t*)smem;                  // [64][72] bf16
    ushort_t* ks = (ushort_t*)(smem + 9216);         // [64][72] bf16 (phase A)
    float*    vs = (float*)(smem + 9216);            // [64][68] f32  (phase B+, aliases ks)
    float*    ps = (float*)(smem + 26624);           // [64][68] f32
    float*    cc  = (float*)(smem + 44032);          // [64]
    float*    exT = (float*)(smem + 44288);          // [64]
    float*    zz  = (float*)(smem + 44544);          // [64]
    float*    den = (float*)(smem + 44800);          // [64]

    const int chunk = blockIdx.x;
    const int bh = blockIdx.y;
    const int b = bh >> 4, h = bh & 15;
    const int tid = threadIdx.x;
    const int wv = tid >> 6, ln = tid & 63;
    const size_t slot = (size_t)bh * NCHUNK + chunk;

    // ---- phase 0: stage q, k (bf16), load logf ----
    if (tid < 64)
        cc[tid] = logf[(size_t)((chunk*64 + tid)*BATCH + b) * HEADS + h];
    #pragma unroll
    for (int it = 0; it < 2; ++it) {
        const int u = it*256 + tid;            // 512 units of 8 elems
        const int j = u >> 3, c8 = (u & 7) * 8;
        const size_t goff = (size_t)((chunk*64 + j)*BATCH + b) * HID + h*HD + c8;
        *(u16x8*)(qs + j*72 + c8) = *(const u16x8*)(Qp + goff);
        *(u16x8*)(ks + j*72 + c8) = *(const u16x8*)(Kp + goff);
    }
    __syncthreads();

    // ---- phase 1: cumsum of log f ----
    if (tid == 0) { float s = 0.f; for (int j = 0; j < 64; ++j) { s += cc[j]; cc[j] = s; } }
    __syncthreads();

    // ---- phase 2: exT/zz (wave 0) + QK^T mfma (all waves) ----
    if (tid < 64) {
        exT[tid] = __expf(cc[tid]);
        zz[tid]  = z0[slot * 64 + tid];
    }
    const int fr = ln & 15;
    const int fk8 = (ln >> 4) * 8;
    f32x4 pacc[4];
    #pragma unroll
    for (int nt = 0; nt < 4; ++nt) pacc[nt] = (f32x4){0.f,0.f,0.f,0.f};
    #pragma unroll
    for (int k0 = 0; k0 < 64; k0 += 32) {
        bf16x8 af = *(const bf16x8*)(qs + (wv*16 + fr)*72 + k0 + fk8);
        #pragma unroll
        for (int nt = 0; nt < 4; ++nt) {
            bf16x8 bfr = *(const bf16x8*)(ks + (nt*16 + fr)*72 + k0 + fk8);
            pacc[nt] = __builtin_amdgcn_mfma_f32_16x16x32_bf16(af, bfr, pacc[nt], 0, 0, 0);
        }
    }
    __syncthreads();   // frag reads done; ks region may now be overwritten

    // ---- phase 3: decay+mask -> ps (f32); stage V -> vs (f32) ----
    {
        const int g4 = (ln >> 4) * 4;
        float cct[4];
        #pragma unroll
        for (int r = 0; r < 4; ++r) cct[r] = cc[wv*16 + g4 + r];
        #pragma unroll
        for (int nt = 0; nt < 4; ++nt) {
            const int j = nt*16 + (ln & 15);
            const float ccj = cc[j];
            #pragma unroll
            for (int r = 0; r < 4; ++r) {
                const int t = wv*16 + g4 + r;
                const float v = (j <= t) ? pacc[nt][r] * __expf(cct[r] - ccj) : 0.f;
                ps[t*68 + j] = v;
            }
        }
    }
    #pragma unroll
    for (int it = 0; it < 2; ++it) {
        const int u = it*256 + tid;
        const int j = u >> 3, c8 = (u & 7) * 8;
        const size_t goff = (size_t)((chunk*64 + j)*BATCH + b) * HID + h*HD + c8;
        u16x8 vraw = *(const u16x8*)(Vp + goff);
        float4 f0, f1;
        f0.x = bf2f(vraw[0]); f0.y = bf2f(vraw[1]); f0.z = bf2f(vraw[2]); f0.w = bf2f(vraw[3]);
        f1.x = bf2f(vraw[4]); f1.y = bf2f(vraw[5]); f1.z = bf2f(vraw[6]); f1.w = bf2f(vraw[7]);
        *(float4*)(vs + j*68 + c8)     = f0;
        *(float4*)(vs + j*68 + c8 + 4) = f1;
    }
    __syncthreads();

    // ---- phase 4: denominators ----
    if (tid < 64) {
        float s = 0.f;
        for (int j = 0; j < 64; ++j) s += ps[tid*68 + j];
        float qzv = 0.f;
        for (int d = 0; d < 64; ++d) qzv += bf2f(qs[tid*72 + d]) * zz[d];
        den[tid] = s + exT[tid] * qzv + 1e-6f;
    }
    __syncthreads();

    // ---- phase 5: outputs ----
    const int t = tid >> 2, eg = (tid & 3) << 4;
    float acc[16] = {};
    for (int jb = 0; jb < 64; jb += 4) {
        const float4 p4 = *(const float4*)(ps + t*68 + jb);
        #pragma unroll
        for (int jj = 0; jj < 4; ++jj) {
            const float p = ((const float*)&p4)[jj];
            const float4* vrow = (const float4*)(vs + (jb+jj)*68 + eg);
            const float4 v0 = vrow[0], v1 = vrow[1], v2 = vrow[2], v3 = vrow[3];
            acc[0]  += p*v0.x;  acc[1]  += p*v0.y;  acc[2]  += p*v0.z;  acc[3]  += p*v0.w;
            acc[4]  += p*v1.x;  acc[5]  += p*v1.y;  acc[6]  += p*v1.z;  acc[7]  += p*v1.w;
            acc[8]  += p*v2.x;  acc[9]  += p*v2.y;  acc[10] += p*v2.z;  acc[11] += p*v2.w;
            acc[12] += p*v3.x;  acc[13] += p*v3.y;  acc[14] += p*v3.z;  acc[15] += p*v3.w;
        }
    }
    float acc2[16] = {};
    const float* S0p = S0 + slot * 4096;
    for (int d = 0; d < 64; ++d) {
        const float q = bf2f(qs[t*72 + d]);
        const float4* srow = (const float4*)(S0p + d*64 + eg);
        const float4 s0 = srow[0], s1 = srow[1], s2 = srow[2], s3 = srow[3];
        acc2[0]  += q*s0.x;  acc2[1]  += q*s0.y;  acc2[2]  += q*s0.z;  acc2[3]  += q*s0.w;
        acc2[4]  += q*s1.x;  acc2[5]  += q*s1.y;  acc2[6]  += q*s1.z;  acc2[7]  += q*s1.w;
        acc2[8]  += q*s2.x;  acc2[9]  += q*s2.y;  acc2[10] += q*s2.z;  acc2[11] += q*s2.w;
        acc2[12] += q*s3.x;  acc2[13] += q*s3.y;  acc2[14] += q*s3.z;  acc2[15] += q*s3.w;
    }
    const float ect = exT[t];
    const float inv = 1.f / den[t];
    u16x8 o0, o1;
    #pragma unroll
    for (int i = 0; i < 8; ++i) o0[i] = f2bf((acc[i]   + ect*acc2[i])   * inv);
    #pragma unroll
    for (int i = 0; i < 8; ++i) o1[i] = f2bf((acc[i+8] + ect*acc2[i+8]) * inv);
    ushort_t* outp = AO + (size_t)((chunk*64 + t)*BATCH + b) * HID + h*HD + eg;
    *(u16x8*)outp       = o0;
    *(u16x8*)(outp + 8) = o1;
}

// ---------------------------------------------------------------------------
extern "C" void kernel_launch(void* const* d_in, const int* in_sizes, int n_in,
                              void* d_out, int out_size, void* d_ws, size_t ws_size,
                              hipStream_t stream) {
    const float* X  = (const float*)d_in[0];
    const float* Wq = (const float*)d_in[1];
    const float* bq = (const float*)d_in[2];
    const float* Wk = (const float*)d_in[3];
    const float* bk = (const float*)d_in[4];
    const float* Wv = (const float*)d_in[5];
    const float* bv = (const float*)d_in[6];
    const float* Wf = (const float*)d_in[7];
    const float* bf = (const float*)d_in[8];
    const float* Wo = (const float*)d_in[9];
    const float* bo = (const float*)d_in[10];

    float* out = (float*)d_out;
    const size_t OUT_SLOT = (size_t)SB * HID;

    char* ws = (char*)d_ws;
    ushort_t* wsXb = (ushort_t*)ws;                         // SB*HID bf16 (X, later attn_out)
    ushort_t* wsWqb = wsXb + (size_t)SB * HID;
    ushort_t* wsWkb = wsWqb + (size_t)HID * HID;
    ushort_t* wsWvb = wsWkb + (size_t)HID * HID;
    ushort_t* wsWob = wsWvb + (size_t)HID * HID;
    ushort_t* wsQ   = wsWob + (size_t)HID * HID;
    ushort_t* wsK   = wsQ + (size_t)SB * HID;
    ushort_t* wsV   = wsK + (size_t)SB * HID;
    float* wsLogf = (float*)(wsV + (size_t)SB * HID);
    float* wsS    = wsLogf + (size_t)SB * HEADS;
    float* wsZ    = wsS + (size_t)BH * NCHUNK * HD * HD;
    float* wsD    = wsZ + (size_t)BH * NCHUNK * HD;

    hipMemsetAsync(out + OUT_SLOT, 0, OUT_SLOT * sizeof(float), stream);

    cvt_f32_bf16<<<(SB*HID/4 + 255)/256, 256, 0, stream>>>(X,  wsXb,  SB*HID/4);
    cvt_f32_bf16<<<(HID*HID/4 + 255)/256, 256, 0, stream>>>(Wq, wsWqb, HID*HID/4);
    cvt_f32_bf16<<<(HID*HID/4 + 255)/256, 256, 0, stream>>>(Wk, wsWkb, HID*HID/4);
    cvt_f32_bf16<<<(HID*HID/4 + 255)/256, 256, 0, stream>>>(Wv, wsWvb, HID*HID/4);
    cvt_f32_bf16<<<(HID*HID/4 + 255)/256, 256, 0, stream>>>(Wo, wsWob, HID*HID/4);

    dim3 ggrid(HID/128, SB/128);
    gemm_mfma<1,1><<<ggrid, 256, 0, stream>>>(wsXb, wsWqb, bq, wsQ, SB, HID, HID);
    gemm_mfma<1,1><<<ggrid, 256, 0, stream>>>(wsXb, wsWkb, bk, wsK, SB, HID, HID);
    gemm_mfma<0,1><<<ggrid, 256, 0, stream>>>(wsXb, wsWvb, bv, wsV, SB, HID, HID);

    fgate_kernel<<<SB, 256, 0, stream>>>(X, Wf, bf, out + 2*OUT_SLOT, wsLogf);

    dim3 sgrid(NCHUNK, BH);
    pass1_kernel<<<sgrid, 256, 0, stream>>>(wsK, wsV, wsLogf, wsS, wsZ, wsD);
    pass2_kernel<<<BH, 256, 0, stream>>>(wsS, wsZ, wsD);
    pass3_kernel<<<sgrid, 256, 0, stream>>>(wsQ, wsK, wsV, wsLogf, wsS, wsZ, wsXb);

    gemm_mfma<0,0><<<ggrid, 256, 0, stream>>>(wsXb, wsWob, bo, out, SB, HID, HID);
}

// Round 4
// 434.166 us; speedup vs baseline: 4.1376x; 1.2001x over previous
//
#include <hip/hip_runtime.h>
#include <hip/hip_bf16.h>
#include <math.h>

// Problem constants
#define S_LEN 2048
#define BATCH 4
#define HID   1024
#define HEADS 16
#define HD    64
#define SB    (S_LEN*BATCH)       // 8192 rows
#define CHUNK 64
#define NCHUNK (S_LEN/CHUNK)      // 32
#define BH    (BATCH*HEADS)       // 64

typedef __bf16 bf16x8 __attribute__((ext_vector_type(8)));
typedef float  f32x4  __attribute__((ext_vector_type(4)));
typedef unsigned short ushort_t;
typedef unsigned short u16x8 __attribute__((ext_vector_type(8)));

__device__ __forceinline__ unsigned short f2bf(float x) {
    union { float f; unsigned int u; } un; un.f = x;
    unsigned int u = un.u;
    unsigned int r = (u + 0x7FFFu + ((u >> 16) & 1u)) >> 16;  // RNE
    return (unsigned short)r;
}
__device__ __forceinline__ float bf2f(unsigned short s) {
    union { unsigned int u; float f; } un; un.u = ((unsigned int)s) << 16;
    return un.f;
}

// ---------------------------------------------------------------------------
// fp32 -> bf16 convert
// ---------------------------------------------------------------------------
__global__ __launch_bounds__(256) void cvt_f32_bf16(
    const float* __restrict__ s, ushort_t* __restrict__ d, int n4)
{
    int i = blockIdx.x * 256 + threadIdx.x;
    if (i < n4) {
        float4 v = ((const float4*)s)[i];
        ushort4 o;
        o.x = f2bf(v.x); o.y = f2bf(v.y); o.z = f2bf(v.z); o.w = f2bf(v.w);
        ((ushort4*)d)[i] = o;
    }
}

// ---------------------------------------------------------------------------
// bf16 MFMA GEMM: Y = X @ W^T + bias (+act).
// ACT=0 none, ACT=1 elu+1.
// OBF=0: fp32 out [row][col]. OBF=1: bf16 out [row][col].
// OBF=2: bf16 out TRANSPOSED per batch: Y[b][col][s] where row = s*BATCH+b.
//        (requires rows aligned to 4 — true: all row bases are mult of 4)
// ---------------------------------------------------------------------------
template<int ACT, int OBF>
__global__ __launch_bounds__(256) void gemm_mfma(
    const ushort_t* __restrict__ X, const ushort_t* __restrict__ W,
    const float* __restrict__ bias, void* __restrict__ Yv,
    int M, int N, int K)
{
    __shared__ ushort_t As[128 * 32];
    __shared__ ushort_t Bs[128 * 32];

    const int tid  = threadIdx.x;
    const int wave = tid >> 6, lane = tid & 63;
    const int waveM = wave >> 1, waveN = wave & 1;
    const int rowBase = blockIdx.y * 128;
    const int colBase = blockIdx.x * 128;

    f32x4 acc[4][4];
    #pragma unroll
    for (int i = 0; i < 4; ++i)
        #pragma unroll
        for (int j = 0; j < 4; ++j)
            acc[i][j] = (f32x4){0.f, 0.f, 0.f, 0.f};

    const int srow = lane >> 2;
    const int scol = (lane & 3) * 8;

    const ushort_t* gA0 = X + (size_t)(rowBase + wave*16 + srow) * K + scol;
    const ushort_t* gB0 = W + (size_t)(colBase + wave*16 + srow) * K + scol;
    ushort_t* lA = As + (wave*16)*32;
    ushort_t* lB = Bs + (wave*16)*32;

    const int fr = lane & 15;
    const int fk = (lane >> 4) * 8;

    for (int k0 = 0; k0 < K; k0 += 32) {
        __builtin_amdgcn_global_load_lds(
            (const __attribute__((address_space(1))) void*)(gA0 + k0),
            (__attribute__((address_space(3))) void*)lA, 16, 0, 0);
        __builtin_amdgcn_global_load_lds(
            (const __attribute__((address_space(1))) void*)(gA0 + (size_t)64*K + k0),
            (__attribute__((address_space(3))) void*)(lA + 64*32), 16, 0, 0);
        __builtin_amdgcn_global_load_lds(
            (const __attribute__((address_space(1))) void*)(gB0 + k0),
            (__attribute__((address_space(3))) void*)lB, 16, 0, 0);
        __builtin_amdgcn_global_load_lds(
            (const __attribute__((address_space(1))) void*)(gB0 + (size_t)64*K + k0),
            (__attribute__((address_space(3))) void*)(lB + 64*32), 16, 0, 0);

        __syncthreads();

        bf16x8 a[4], b[4];
        #pragma unroll
        for (int i = 0; i < 4; ++i)
            a[i] = *(const bf16x8*)(As + (waveM*64 + i*16 + fr)*32 + fk);
        #pragma unroll
        for (int j = 0; j < 4; ++j)
            b[j] = *(const bf16x8*)(Bs + (waveN*64 + j*16 + fr)*32 + fk);

        #pragma unroll
        for (int i = 0; i < 4; ++i)
            #pragma unroll
            for (int j = 0; j < 4; ++j)
                acc[i][j] = __builtin_amdgcn_mfma_f32_16x16x32_bf16(
                    a[i], b[j], acc[i][j], 0, 0, 0);

        __syncthreads();
    }

    const int er = (lane >> 4) * 4;
    const int ec = lane & 15;
    #pragma unroll
    for (int i = 0; i < 4; ++i) {
        #pragma unroll
        for (int j = 0; j < 4; ++j) {
            const int r0 = rowBase + waveM*64 + i*16 + er;   // multiple of 4
            const int c  = colBase + waveN*64 + j*16 + ec;
            const float bv = bias[c];
            #pragma unroll
            for (int k = 0; k < 4; ++k) {
                float v = acc[i][j][k] + bv;
                if (ACT == 1) v = (v > 0.f) ? (v + 1.f) : __expf(v);
                if (OBF == 0)
                    ((float*)Yv)[(size_t)(r0 + k) * N + c] = v;
                else if (OBF == 1)
                    ((ushort_t*)Yv)[(size_t)(r0 + k) * N + c] = f2bf(v);
                else {
                    // row = r0+k = s*4 + b  ->  b = k, s = r0>>2
                    ((ushort_t*)Yv)[(size_t)k * ((size_t)HID * S_LEN)
                                    + (size_t)c * S_LEN + (r0 >> 2)] = f2bf(v);
                }
            }
        }
    }
}

// ---------------------------------------------------------------------------
// Forget-gate: f = sigmoid(X @ Wf^T + bf) -> f_out (fp32), log f -> ws.
// ---------------------------------------------------------------------------
__global__ __launch_bounds__(256) void fgate_kernel(
    const float* __restrict__ X, const float* __restrict__ Wf,
    const float* __restrict__ bf,
    float* __restrict__ f_out, float* __restrict__ logf_out)
{
    __shared__ float xs[HID];
    const int r = blockIdx.x;
    const int tid = threadIdx.x;

    ((float4*)xs)[tid] = ((const float4*)(X + (size_t)r * HID))[tid];
    __syncthreads();

    const int wave = tid >> 6, lane = tid & 63;
    for (int n = wave; n < HEADS; n += 4) {
        const float* w = Wf + n * HID;
        float s = 0.f;
        for (int kk = lane; kk < HID; kk += 64) s += xs[kk] * w[kk];
        #pragma unroll
        for (int off = 32; off > 0; off >>= 1) s += __shfl_down(s, off);
        if (lane == 0) {
            s += bf[n];
            float fv = 1.f / (1.f + __expf(-s));
            f_out[(size_t)r * HEADS + n]    = fv;
            logf_out[(size_t)r * HEADS + n] = __logf(fv);
        }
    }
}

// ---------------------------------------------------------------------------
// Pass 1: per (bh, chunk) chunk-local contributions, TRANSPOSED state:
//   ScT[e][d] = sum_j exd_j v[j][e] k[j][d]; z[d] = sum_j exd_j k[j][d]
//   exd_j = exp(c_63 - c_j), D = exp(c_63). Cumsum via wave shuffle scan.
// V read from transposed global layout VT[b][col][s].
// ---------------------------------------------------------------------------
__global__ __launch_bounds__(256) void pass1_kernel(
    const ushort_t* __restrict__ Kp, const ushort_t* __restrict__ VTp,
    const float* __restrict__ logf,
    float* __restrict__ Schunk, float* __restrict__ zchunk,
    float* __restrict__ Dchunk)
{
    const int chunk = blockIdx.x;
    const int bh = blockIdx.y;
    const int b = bh >> 4, h = bh & 15;
    const int tid = threadIdx.x;
    const size_t slot = (size_t)bh * NCHUNK + chunk;

    __shared__ float ks[64][65];   // [j][d]
    __shared__ float vs[64][65];   // V^T: [e][j]
    __shared__ float exd[64];

    if (tid < 64) {
        float v = logf[(size_t)((chunk*64 + tid)*BATCH + b) * HEADS + h];
        #pragma unroll
        for (int off = 1; off < 64; off <<= 1) {
            float n = __shfl_up(v, off);
            if (tid >= off) v += n;
        }
        const float tot = __shfl(v, 63);
        exd[tid] = __expf(tot - v);
        if (tid == 63) Dchunk[slot] = __expf(tot);
    }

    #pragma unroll
    for (int it = 0; it < 2; ++it) {
        const int u = it*256 + tid;
        const int r = u >> 3, c8 = (u & 7) * 8;
        u16x8 kk = *(const u16x8*)(Kp + (size_t)((chunk*64 + r)*BATCH + b)*HID + h*HD + c8);
        u16x8 vv = *(const u16x8*)(VTp + (size_t)b*((size_t)HID*S_LEN)
                                   + (size_t)(h*HD + r)*S_LEN + chunk*64 + c8);
        #pragma unroll
        for (int i = 0; i < 8; ++i) {
            ks[r][c8+i] = bf2f(kk[i]);
            vs[r][c8+i] = bf2f(vv[i]);
        }
    }
    __syncthreads();

    const int e = tid >> 2, dg = (tid & 3) << 4;
    float acc[16] = {};
    for (int j = 0; j < 64; ++j) {
        const float wv = exd[j] * vs[e][j];
        #pragma unroll
        for (int i = 0; i < 16; ++i) acc[i] += wv * ks[j][dg + i];
    }
    float* sp = Schunk + slot * 4096;
    #pragma unroll
    for (int i = 0; i < 16; ++i) sp[e*64 + dg + i] = acc[i];

    if (tid < 64) {
        float z = 0.f;
        for (int j = 0; j < 64; ++j) z += exd[j] * ks[j][tid];
        zchunk[slot * 64 + tid] = z;
    }
}

// ---------------------------------------------------------------------------
// Pass 2: sequential over 32 chunks per (bh); elementwise on S^T layout;
// in-place replace contributions with the state ENTERING the chunk.
// ---------------------------------------------------------------------------
__global__ __launch_bounds__(256) void pass2_kernel(
    float* __restrict__ Schunk, float* __restrict__ zchunk,
    const float* __restrict__ Dchunk)
{
    const int bh = blockIdx.x;
    const int tid = threadIdx.x;

    float Sprev[16];
    #pragma unroll
    for (int i = 0; i < 16; ++i) Sprev[i] = 0.f;
    float zprev = 0.f;

    const size_t base  = (size_t)bh * NCHUNK * 4096;
    const size_t zbase = (size_t)bh * NCHUNK * 64;

    for (int c = 0; c < NCHUNK; ++c) {
        const float D = Dchunk[bh * NCHUNK + c];
        float* sp = Schunk + base + (size_t)c * 4096;
        float contrib[16];
        #pragma unroll
        for (int i = 0; i < 16; ++i) contrib[i] = sp[i*256 + tid];
        #pragma unroll
        for (int i = 0; i < 16; ++i) {
            sp[i*256 + tid] = Sprev[i];
            Sprev[i] = D * Sprev[i] + contrib[i];
        }
        if (tid < 64) {
            float* zp = zchunk + zbase + (size_t)c * 64;
            const float zc = zp[tid];
            zp[tid] = zprev;
            zprev = D * zprev + zc;
        }
    }
}

// ---------------------------------------------------------------------------
// Pass 3 (full-MFMA): per (bh, chunk) attention outputs -> bf16 AO.
//   B1: stage qs/ks (bf16), wave0: shfl-scan cumsum -> cc/exT.
//   QK^T MFMA (8/wave); wave0: qz[t] = q_t . z0.
//   B2 (frees ks region). Stage V^T (coalesced from VT global); decay+mask
//   P -> bf16 psA (A-layout); rowsums via shfl_xor -> den.
//   B3. PV MFMA + qS0 MFMA (B-frags from global S0T fp32->bf16); write AO.
// LDS: qs 9216 | ks/vsT 9216 | psA 9216 | scalars 1024 = 28672 B -> 5 blk/CU.
// ---------------------------------------------------------------------------
__global__ __launch_bounds__(256) void pass3_kernel(
    const ushort_t* __restrict__ Qp, const ushort_t* __restrict__ Kp,
    const ushort_t* __restrict__ VTp, const float* __restrict__ logf,
    const float* __restrict__ S0, const float* __restrict__ z0,
    ushort_t* __restrict__ AO)
{
    __shared__ __align__(16) char smem[28672];
    ushort_t* qs  = (ushort_t*)smem;               // [64][72] bf16 (t rows)
    ushort_t* ks  = (ushort_t*)(smem + 9216);      // [64][72] bf16 (j rows) phase A
    ushort_t* vsT = (ushort_t*)(smem + 9216);      // [64][72] bf16 (e rows, j cols) phase B — aliases ks
    ushort_t* psA = (ushort_t*)(smem + 18432);     // [64][72] bf16 P (t rows, j cols)
    float* cc  = (float*)(smem + 27648);           // [64] cumsum logf
    float* exT = (float*)(smem + 27904);           // [64] exp(cc)
    float* qz  = (float*)(smem + 28160);           // [64] q_t . z0
    float* den = (float*)(smem + 28416);           // [64]

    const int chunk = blockIdx.x;
    const int bh = blockIdx.y;
    const int b = bh >> 4, h = bh & 15;
    const int tid = threadIdx.x;
    const int wv = tid >> 6, ln = tid & 63;
    const int fr = ln & 15, q4 = ln >> 4;          // fragment row, quad
    const size_t slot = (size_t)bh * NCHUNK + chunk;

    // ---- phase 0: wave0 scan; all stage q,k ----
    if (tid < 64) {
        float v = logf[(size_t)((chunk*64 + tid)*BATCH + b) * HEADS + h];
        #pragma unroll
        for (int off = 1; off < 64; off <<= 1) {
            float n = __shfl_up(v, off);
            if (tid >= off) v += n;
        }
        cc[tid]  = v;
        exT[tid] = __expf(v);
    }
    #pragma unroll
    for (int it = 0; it < 2; ++it) {
        const int u = it*256 + tid;
        const int r = u >> 3, c8 = (u & 7) * 8;
        const size_t goff = (size_t)((chunk*64 + r)*BATCH + b) * HID + h*HD + c8;
        *(u16x8*)(qs + r*72 + c8) = *(const u16x8*)(Qp + goff);
        *(u16x8*)(ks + r*72 + c8) = *(const u16x8*)(Kp + goff);
    }
    __syncthreads();   // B1

    // ---- phase 1: QK^T MFMA; wave0: qz ----
    f32x4 pacc[4];
    #pragma unroll
    for (int nt = 0; nt < 4; ++nt) pacc[nt] = (f32x4){0.f,0.f,0.f,0.f};
    #pragma unroll
    for (int k0 = 0; k0 < 64; k0 += 32) {
        bf16x8 af = *(const bf16x8*)(qs + (wv*16 + fr)*72 + k0 + q4*8);
        #pragma unroll
        for (int nt = 0; nt < 4; ++nt) {
            bf16x8 bfr = *(const bf16x8*)(ks + (nt*16 + fr)*72 + k0 + q4*8);
            pacc[nt] = __builtin_amdgcn_mfma_f32_16x16x32_bf16(af, bfr, pacc[nt], 0, 0, 0);
        }
    }
    if (tid < 64) {
        float zown = z0[slot * 64 + tid];
        float s = 0.f;
        for (int d = 0; d < 64; ++d) {
            const float zd = __shfl(zown, d);
            s += bf2f(qs[tid*72 + d]) * zd;
        }
        qz[tid] = s;
    }
    __syncthreads();   // B2 — ks reads + qz done; vsT may overwrite ks

    // ---- phase 2: stage V^T; P decay+mask -> psA bf16; rowsum -> den ----
    #pragma unroll
    for (int it = 0; it < 2; ++it) {
        const int u = it*256 + tid;
        const int e = u >> 3, j8 = (u & 7) * 8;
        *(u16x8*)(vsT + e*72 + j8) =
            *(const u16x8*)(VTp + (size_t)b*((size_t)HID*S_LEN)
                            + (size_t)(h*HD + e)*S_LEN + chunk*64 + j8);
    }
    {
        float rs[4] = {0.f, 0.f, 0.f, 0.f};
        float cct[4];
        #pragma unroll
        for (int r = 0; r < 4; ++r) cct[r] = cc[wv*16 + q4*4 + r];
        #pragma unroll
        for (int nt = 0; nt < 4; ++nt) {
            const int j = nt*16 + fr;
            const float ccj = cc[j];
            #pragma unroll
            for (int r = 0; r < 4; ++r) {
                const int t = wv*16 + q4*4 + r;
                float p = (j <= t) ? pacc[nt][r] * __expf(cct[r] - ccj) : 0.f;
                rs[r] += p;
                psA[t*72 + j] = f2bf(p);
            }
        }
        #pragma unroll
        for (int m = 1; m < 16; m <<= 1) {
            #pragma unroll
            for (int r = 0; r < 4; ++r) rs[r] += __shfl_xor(rs[r], m);
        }
        if (fr == 0) {
            #pragma unroll
            for (int r = 0; r < 4; ++r) {
                const int t = wv*16 + q4*4 + r;
                den[t] = rs[r] + exT[t] * qz[t] + 1e-6f;
            }
        }
    }
    __syncthreads();   // B3

    // ---- phase 3: PV + qS0 MFMAs, combine, write AO ----
    f32x4 oacc[4], oacc2[4];
    #pragma unroll
    for (int nt = 0; nt < 4; ++nt) {
        oacc[nt]  = (f32x4){0.f,0.f,0.f,0.f};
        oacc2[nt] = (f32x4){0.f,0.f,0.f,0.f};
    }
    const float* S0p = S0 + slot * 4096;
    #pragma unroll
    for (int k0 = 0; k0 < 64; k0 += 32) {
        const int k8 = k0 + q4*8;
        bf16x8 ap = *(const bf16x8*)(psA + (wv*16 + fr)*72 + k8);
        bf16x8 aq = *(const bf16x8*)(qs  + (wv*16 + fr)*72 + k8);
        #pragma unroll
        for (int nt = 0; nt < 4; ++nt) {
            bf16x8 bv = *(const bf16x8*)(vsT + (nt*16 + fr)*72 + k8);
            oacc[nt] = __builtin_amdgcn_mfma_f32_16x16x32_bf16(ap, bv, oacc[nt], 0, 0, 0);
            // S0^T B-frag from global fp32 -> bf16
            f32x4 s0a = *(const f32x4*)(S0p + (nt*16 + fr)*64 + k8);
            f32x4 s0b = *(const f32x4*)(S0p + (nt*16 + fr)*64 + k8 + 4);
            u16x8 sb;
            #pragma unroll
            for (int i = 0; i < 4; ++i) { sb[i] = f2bf(s0a[i]); sb[4+i] = f2bf(s0b[i]); }
            oacc2[nt] = __builtin_amdgcn_mfma_f32_16x16x32_bf16(aq, *(bf16x8*)&sb, oacc2[nt], 0, 0, 0);
        }
    }
    #pragma unroll
    for (int nt = 0; nt < 4; ++nt) {
        const int e = nt*16 + fr;
        #pragma unroll
        for (int r = 0; r < 4; ++r) {
            const int t = wv*16 + q4*4 + r;
            const float v = (oacc[nt][r] + exT[t] * oacc2[nt][r]) / den[t];
            AO[(size_t)((chunk*64 + t)*BATCH + b) * HID + h*HD + e] = f2bf(v);
        }
    }
}

// ---------------------------------------------------------------------------
extern "C" void kernel_launch(void* const* d_in, const int* in_sizes, int n_in,
                              void* d_out, int out_size, void* d_ws, size_t ws_size,
                              hipStream_t stream) {
    const float* X  = (const float*)d_in[0];
    const float* Wq = (const float*)d_in[1];
    const float* bq = (const float*)d_in[2];
    const float* Wk = (const float*)d_in[3];
    const float* bk = (const float*)d_in[4];
    const float* Wv = (const float*)d_in[5];
    const float* bv = (const float*)d_in[6];
    const float* Wf = (const float*)d_in[7];
    const float* bf = (const float*)d_in[8];
    const float* Wo = (const float*)d_in[9];
    const float* bo = (const float*)d_in[10];

    float* out = (float*)d_out;
    const size_t OUT_SLOT = (size_t)SB * HID;

    char* ws = (char*)d_ws;
    ushort_t* wsXb  = (ushort_t*)ws;                        // SB*HID bf16 (X, later attn_out)
    ushort_t* wsWqb = wsXb + (size_t)SB * HID;
    ushort_t* wsWkb = wsWqb + (size_t)HID * HID;
    ushort_t* wsWvb = wsWkb + (size_t)HID * HID;
    ushort_t* wsWob = wsWvb + (size_t)HID * HID;
    ushort_t* wsQ   = wsWob + (size_t)HID * HID;            // [row][col] bf16
    ushort_t* wsK   = wsQ + (size_t)SB * HID;               // [row][col] bf16
    ushort_t* wsVT  = wsK + (size_t)SB * HID;               // [b][col][s] bf16 (transposed)
    float* wsLogf = (float*)(wsVT + (size_t)SB * HID);
    float* wsS    = wsLogf + (size_t)SB * HEADS;            // S^T chunks -> S0^T
    float* wsZ    = wsS + (size_t)BH * NCHUNK * HD * HD;
    float* wsD    = wsZ + (size_t)BH * NCHUNK * HD;

    hipMemsetAsync(out + OUT_SLOT, 0, OUT_SLOT * sizeof(float), stream);

    cvt_f32_bf16<<<(SB*HID/4 + 255)/256, 256, 0, stream>>>(X,  wsXb,  SB*HID/4);
    cvt_f32_bf16<<<(HID*HID/4 + 255)/256, 256, 0, stream>>>(Wq, wsWqb, HID*HID/4);
    cvt_f32_bf16<<<(HID*HID/4 + 255)/256, 256, 0, stream>>>(Wk, wsWkb, HID*HID/4);
    cvt_f32_bf16<<<(HID*HID/4 + 255)/256, 256, 0, stream>>>(Wv, wsWvb, HID*HID/4);
    cvt_f32_bf16<<<(HID*HID/4 + 255)/256, 256, 0, stream>>>(Wo, wsWob, HID*HID/4);

    dim3 ggrid(HID/128, SB/128);
    gemm_mfma<1,1><<<ggrid, 256, 0, stream>>>(wsXb, wsWqb, bq, wsQ,  SB, HID, HID);
    gemm_mfma<1,1><<<ggrid, 256, 0, stream>>>(wsXb, wsWkb, bk, wsK,  SB, HID, HID);
    gemm_mfma<0,2><<<ggrid, 256, 0, stream>>>(wsXb, wsWvb, bv, wsVT, SB, HID, HID);

    fgate_kernel<<<SB, 256, 0, stream>>>(X, Wf, bf, out + 2*OUT_SLOT, wsLogf);

    dim3 sgrid(NCHUNK, BH);
    pass1_kernel<<<sgrid, 256, 0, stream>>>(wsK, wsVT, wsLogf, wsS, wsZ, wsD);
    pass2_kernel<<<BH, 256, 0, stream>>>(wsS, wsZ, wsD);
    pass3_kernel<<<sgrid, 256, 0, stream>>>(wsQ, wsK, wsVT, wsLogf, wsS, wsZ, wsXb);

    gemm_mfma<0,0><<<ggrid, 256, 0, stream>>>(wsXb, wsWob, bo, out, SB, HID, HID);
}

// Round 5
// 330.577 us; speedup vs baseline: 5.4342x; 1.3134x over previous
//
#include <hip/hip_runtime.h>
#include <hip/hip_bf16.h>
#include <math.h>

// Problem constants
#define S_LEN 2048
#define BATCH 4
#define HID   1024
#define HEADS 16
#define HD    64
#define SB    (S_LEN*BATCH)       // 8192 rows
#define CHUNK 64
#define NCHUNK (S_LEN/CHUNK)      // 32
#define BH    (BATCH*HEADS)       // 64
#define NSTK  3200                // 1024*3 (QKV) + 16 (F) padded to 25*128

typedef __bf16 bf16x8 __attribute__((ext_vector_type(8)));
typedef float  f32x4  __attribute__((ext_vector_type(4)));
typedef unsigned short ushort_t;
typedef unsigned short u16x8 __attribute__((ext_vector_type(8)));

__device__ __forceinline__ unsigned short f2bf(float x) {
    union { float f; unsigned int u; } un; un.f = x;
    unsigned int u = un.u;
    unsigned int r = (u + 0x7FFFu + ((u >> 16) & 1u)) >> 16;  // RNE
    return (unsigned short)r;
}
__device__ __forceinline__ float bf2f(unsigned short s) {
    union { unsigned int u; float f; } un; un.u = ((unsigned int)s) << 16;
    return un.f;
}

// ---------------------------------------------------------------------------
// Prep kernel: one dispatch does
//   [0, NXU)            : X fp32 -> bf16 (wsXb)
//   [NXU, +NW1)         : stacked weight build Wstk[3200][1024] bf16
//                         rows 0-1023 Wq | 1024-2047 Wk | 2048-3071 Wv |
//                         3072-3087 Wf | 3088-3199 zeros
//   [NXU+NW1, +NW2)     : Wo fp32 -> bf16 (wsWob)
//   [NXU+NW1+NW2, +NBU) : stacked bias bstk[3200] fp32
// Units of 4 elements each.
// ---------------------------------------------------------------------------
#define NXU (SB*HID/4)          // 2097152
#define NW1 (NSTK*HID/4)        // 819200
#define NW2 (HID*HID/4)         // 262144
#define NBU (NSTK/4)            // 800
#define NTOT (NXU+NW1+NW2+NBU)

__global__ __launch_bounds__(256) void prep_kernel(
    const float* __restrict__ X,  const float* __restrict__ Wq,
    const float* __restrict__ Wk, const float* __restrict__ Wv,
    const float* __restrict__ Wf, const float* __restrict__ Wo,
    const float* __restrict__ bq, const float* __restrict__ bk,
    const float* __restrict__ bv, const float* __restrict__ bf,
    ushort_t* __restrict__ Xb, ushort_t* __restrict__ Wstk,
    ushort_t* __restrict__ Wob, float* __restrict__ bstk)
{
    const int i = blockIdx.x * 256 + threadIdx.x;
    if (i < NXU) {
        float4 v = ((const float4*)X)[i];
        ushort4 o; o.x=f2bf(v.x); o.y=f2bf(v.y); o.z=f2bf(v.z); o.w=f2bf(v.w);
        ((ushort4*)Xb)[i] = o;
    } else if (i < NXU + NW1) {
        const int idx4 = (i - NXU) * 4;
        const int row = idx4 >> 10, col = idx4 & 1023;
        float4 v;
        if      (row < 1024) v = *(const float4*)(Wq + (size_t)row*HID + col);
        else if (row < 2048) v = *(const float4*)(Wk + (size_t)(row-1024)*HID + col);
        else if (row < 3072) v = *(const float4*)(Wv + (size_t)(row-2048)*HID + col);
        else if (row < 3088) v = *(const float4*)(Wf + (size_t)(row-3072)*HID + col);
        else                 v = make_float4(0.f,0.f,0.f,0.f);
        ushort4 o; o.x=f2bf(v.x); o.y=f2bf(v.y); o.z=f2bf(v.z); o.w=f2bf(v.w);
        *(ushort4*)(Wstk + idx4) = o;
    } else if (i < NXU + NW1 + NW2) {
        const int idx4 = (i - NXU - NW1) * 4;
        float4 v = *(const float4*)(Wo + idx4);
        ushort4 o; o.x=f2bf(v.x); o.y=f2bf(v.y); o.z=f2bf(v.z); o.w=f2bf(v.w);
        *(ushort4*)(Wob + idx4) = o;
    } else if (i < NTOT) {
        const int idx4 = (i - NXU - NW1 - NW2) * 4;
        #pragma unroll
        for (int t = 0; t < 4; ++t) {
            const int c = idx4 + t;
            float v;
            if      (c < 1024) v = bq[c];
            else if (c < 2048) v = bk[c-1024];
            else if (c < 3072) v = bv[c-2048];
            else if (c < 3088) v = bf[c-3072];
            else               v = 0.f;
            bstk[c] = v;
        }
    }
}

// ---------------------------------------------------------------------------
// Fused QKV+F GEMM: S = Xb[8192,1024] @ Wstk[3200,1024]^T + bstk.
// Epilogue by column group:
//   [0,1024)    Q: elu+1 -> wsQ bf16 [row][col]
//   [1024,2048) K: elu+1 -> wsK bf16 [row][col]  AND wsKT bf16 [b][col][s]
//   [2048,3072) V: none  -> wsVT bf16 [b][col][s]
//   [3072,3088) F: sigmoid -> f_out fp32 [row][n]; logf=-log(1+e^-s) -> wsLogf
//   [3088,3200) discarded
// m97 structure: 128x128 tile, BK=32, global_load_lds x16.
// ---------------------------------------------------------------------------
__global__ __launch_bounds__(256) void qkvf_gemm(
    const ushort_t* __restrict__ X, const ushort_t* __restrict__ W,
    const float* __restrict__ bias,
    ushort_t* __restrict__ Q, ushort_t* __restrict__ Kr,
    ushort_t* __restrict__ KT, ushort_t* __restrict__ VT,
    float* __restrict__ f_out, float* __restrict__ logf_out)
{
    __shared__ ushort_t As[128 * 32];
    __shared__ ushort_t Bs[128 * 32];

    const int tid  = threadIdx.x;
    const int wave = tid >> 6, lane = tid & 63;
    const int waveM = wave >> 1, waveN = wave & 1;
    const int rowBase = blockIdx.y * 128;
    const int colBase = blockIdx.x * 128;
    const int K = HID;

    f32x4 acc[4][4];
    #pragma unroll
    for (int i = 0; i < 4; ++i)
        #pragma unroll
        for (int j = 0; j < 4; ++j)
            acc[i][j] = (f32x4){0.f, 0.f, 0.f, 0.f};

    const int srow = lane >> 2;
    const int scol = (lane & 3) * 8;

    const ushort_t* gA0 = X + (size_t)(rowBase + wave*16 + srow) * K + scol;
    const ushort_t* gB0 = W + (size_t)(colBase + wave*16 + srow) * K + scol;
    ushort_t* lA = As + (wave*16)*32;
    ushort_t* lB = Bs + (wave*16)*32;

    const int fr = lane & 15;
    const int fk = (lane >> 4) * 8;

    for (int k0 = 0; k0 < K; k0 += 32) {
        __builtin_amdgcn_global_load_lds(
            (const __attribute__((address_space(1))) void*)(gA0 + k0),
            (__attribute__((address_space(3))) void*)lA, 16, 0, 0);
        __builtin_amdgcn_global_load_lds(
            (const __attribute__((address_space(1))) void*)(gA0 + (size_t)64*K + k0),
            (__attribute__((address_space(3))) void*)(lA + 64*32), 16, 0, 0);
        __builtin_amdgcn_global_load_lds(
            (const __attribute__((address_space(1))) void*)(gB0 + k0),
            (__attribute__((address_space(3))) void*)lB, 16, 0, 0);
        __builtin_amdgcn_global_load_lds(
            (const __attribute__((address_space(1))) void*)(gB0 + (size_t)64*K + k0),
            (__attribute__((address_space(3))) void*)(lB + 64*32), 16, 0, 0);

        __syncthreads();

        bf16x8 a[4], b[4];
        #pragma unroll
        for (int i = 0; i < 4; ++i)
            a[i] = *(const bf16x8*)(As + (waveM*64 + i*16 + fr)*32 + fk);
        #pragma unroll
        for (int j = 0; j < 4; ++j)
            b[j] = *(const bf16x8*)(Bs + (waveN*64 + j*16 + fr)*32 + fk);

        #pragma unroll
        for (int i = 0; i < 4; ++i)
            #pragma unroll
            for (int j = 0; j < 4; ++j)
                acc[i][j] = __builtin_amdgcn_mfma_f32_16x16x32_bf16(
                    a[i], b[j], acc[i][j], 0, 0, 0);

        __syncthreads();
    }

    const int er = (lane >> 4) * 4;
    const int ec = lane & 15;
    #pragma unroll
    for (int i = 0; i < 4; ++i) {
        #pragma unroll
        for (int j = 0; j < 4; ++j) {
            const int r0 = rowBase + waveM*64 + i*16 + er;   // multiple of 4
            const int c0 = colBase + waveN*64 + j*16;        // lane-uniform
            if (c0 >= 3088) continue;
            const int c  = c0 + ec;
            const float bv = bias[c];
            #pragma unroll
            for (int k = 0; k < 4; ++k) {
                float v = acc[i][j][k] + bv;
                const int r = r0 + k;
                const int s = r >> 2, bb = r & 3;
                if (c0 < 1024) {
                    v = (v > 0.f) ? (v + 1.f) : __expf(v);
                    Q[(size_t)r * HID + c] = f2bf(v);
                } else if (c0 < 2048) {
                    v = (v > 0.f) ? (v + 1.f) : __expf(v);
                    const int cc = c - 1024;
                    const ushort_t h = f2bf(v);
                    Kr[(size_t)r * HID + cc] = h;
                    KT[(size_t)bb * ((size_t)HID*S_LEN) + (size_t)cc * S_LEN + s] = h;
                } else if (c0 < 3072) {
                    const int cc = c - 2048;
                    VT[(size_t)bb * ((size_t)HID*S_LEN) + (size_t)cc * S_LEN + s] = f2bf(v);
                } else {
                    const int n = c - 3072;
                    const float fv = 1.f / (1.f + __expf(-v));
                    f_out[(size_t)r * HEADS + n]    = fv;
                    logf_out[(size_t)r * HEADS + n] = -__logf(1.f + __expf(-v));
                }
            }
        }
    }
}

// ---------------------------------------------------------------------------
// Output GEMM: out = AO[8192,1024] @ Wo[1024,1024]^T + bo (fp32), and writes
// zeros into out slot 1 (fused memset).
// ---------------------------------------------------------------------------
__global__ __launch_bounds__(256) void gemm_out(
    const ushort_t* __restrict__ X, const ushort_t* __restrict__ W,
    const float* __restrict__ bias, float* __restrict__ Y,
    float* __restrict__ Yzero)
{
    __shared__ ushort_t As[128 * 32];
    __shared__ ushort_t Bs[128 * 32];

    const int tid  = threadIdx.x;
    const int wave = tid >> 6, lane = tid & 63;
    const int waveM = wave >> 1, waveN = wave & 1;
    const int rowBase = blockIdx.y * 128;
    const int colBase = blockIdx.x * 128;
    const int K = HID, N = HID;

    f32x4 acc[4][4];
    #pragma unroll
    for (int i = 0; i < 4; ++i)
        #pragma unroll
        for (int j = 0; j < 4; ++j)
            acc[i][j] = (f32x4){0.f, 0.f, 0.f, 0.f};

    const int srow = lane >> 2;
    const int scol = (lane & 3) * 8;

    const ushort_t* gA0 = X + (size_t)(rowBase + wave*16 + srow) * K + scol;
    const ushort_t* gB0 = W + (size_t)(colBase + wave*16 + srow) * K + scol;
    ushort_t* lA = As + (wave*16)*32;
    ushort_t* lB = Bs + (wave*16)*32;

    const int fr = lane & 15;
    const int fk = (lane >> 4) * 8;

    for (int k0 = 0; k0 < K; k0 += 32) {
        __builtin_amdgcn_global_load_lds(
            (const __attribute__((address_space(1))) void*)(gA0 + k0),
            (__attribute__((address_space(3))) void*)lA, 16, 0, 0);
        __builtin_amdgcn_global_load_lds(
            (const __attribute__((address_space(1))) void*)(gA0 + (size_t)64*K + k0),
            (__attribute__((address_space(3))) void*)(lA + 64*32), 16, 0, 0);
        __builtin_amdgcn_global_load_lds(
            (const __attribute__((address_space(1))) void*)(gB0 + k0),
            (__attribute__((address_space(3))) void*)lB, 16, 0, 0);
        __builtin_amdgcn_global_load_lds(
            (const __attribute__((address_space(1))) void*)(gB0 + (size_t)64*K + k0),
            (__attribute__((address_space(3))) void*)(lB + 64*32), 16, 0, 0);

        __syncthreads();

        bf16x8 a[4], b[4];
        #pragma unroll
        for (int i = 0; i < 4; ++i)
            a[i] = *(const bf16x8*)(As + (waveM*64 + i*16 + fr)*32 + fk);
        #pragma unroll
        for (int j = 0; j < 4; ++j)
            b[j] = *(const bf16x8*)(Bs + (waveN*64 + j*16 + fr)*32 + fk);

        #pragma unroll
        for (int i = 0; i < 4; ++i)
            #pragma unroll
            for (int j = 0; j < 4; ++j)
                acc[i][j] = __builtin_amdgcn_mfma_f32_16x16x32_bf16(
                    a[i], b[j], acc[i][j], 0, 0, 0);

        __syncthreads();
    }

    const int er = (lane >> 4) * 4;
    const int ec = lane & 15;
    #pragma unroll
    for (int i = 0; i < 4; ++i) {
        #pragma unroll
        for (int j = 0; j < 4; ++j) {
            const int r0 = rowBase + waveM*64 + i*16 + er;
            const int c  = colBase + waveN*64 + j*16 + ec;
            const float bv = bias[c];
            #pragma unroll
            for (int k = 0; k < 4; ++k) {
                const size_t off = (size_t)(r0 + k) * N + c;
                Y[off] = acc[i][j][k] + bv;
                Yzero[off] = 0.f;
            }
        }
    }
}

// ---------------------------------------------------------------------------
// Pass 1 (MFMA): per (bh, chunk):
//   ScT[e][d] = sum_j v[j][e] * (exd_j k[j][d]);  z[d] = sum_j exd_j k[j][d]
//   exd_j = exp(c_63 - c_j);  D = exp(c_63)
// A = V^T (raw), B = decayed K^T (exd applied at staging). z via A=ones MFMA.
// ---------------------------------------------------------------------------
__global__ __launch_bounds__(256) void pass1_kernel(
    const ushort_t* __restrict__ KTp, const ushort_t* __restrict__ VTp,
    const float* __restrict__ logf,
    float* __restrict__ Schunk, float* __restrict__ zchunk,
    float* __restrict__ Dchunk)
{
    __shared__ __align__(16) char smem[18688];
    ushort_t* vsT = (ushort_t*)smem;            // [64][72] V^T raw
    ushort_t* kTd = (ushort_t*)(smem + 9216);   // [64][72] K^T decayed
    float*    exd = (float*)(smem + 18432);     // [64]

    const int chunk = blockIdx.x;
    const int bh = blockIdx.y;
    const int b = bh >> 4, h = bh & 15;
    const int tid = threadIdx.x;
    const int wv = tid >> 6, ln = tid & 63;
    const int fr = ln & 15, q4 = ln >> 4;
    const size_t slot = (size_t)bh * NCHUNK + chunk;

    // register-preload both tiles (overlaps wave0 scan)
    u16x8 vreg[2], kreg[2];
    #pragma unroll
    for (int it = 0; it < 2; ++it) {
        const int u = it*256 + tid;
        const int r = u >> 3, j8 = (u & 7) * 8;
        const size_t base = (size_t)b * ((size_t)HID*S_LEN)
                          + (size_t)(h*HD + r) * S_LEN + chunk*64 + j8;
        vreg[it] = *(const u16x8*)(VTp + base);
        kreg[it] = *(const u16x8*)(KTp + base);
    }
    if (tid < 64) {
        float v = logf[(size_t)((chunk*64 + tid)*BATCH + b) * HEADS + h];
        #pragma unroll
        for (int off = 1; off < 64; off <<= 1) {
            float n = __shfl_up(v, off);
            if (tid >= off) v += n;
        }
        const float tot = __shfl(v, 63);
        exd[tid] = __expf(tot - v);
        if (tid == 63) Dchunk[slot] = __expf(tot);
    }
    __syncthreads();

    #pragma unroll
    for (int it = 0; it < 2; ++it) {
        const int u = it*256 + tid;
        const int r = u >> 3, j8 = (u & 7) * 8;
        *(u16x8*)(vsT + r*72 + j8) = vreg[it];
        u16x8 kd;
        #pragma unroll
        for (int i = 0; i < 8; ++i) kd[i] = f2bf(bf2f(kreg[it][i]) * exd[j8+i]);
        *(u16x8*)(kTd + r*72 + j8) = kd;
    }
    __syncthreads();

    f32x4 acc[4];
    #pragma unroll
    for (int nt = 0; nt < 4; ++nt) acc[nt] = (f32x4){0.f,0.f,0.f,0.f};
    #pragma unroll
    for (int k0 = 0; k0 < 64; k0 += 32) {
        bf16x8 av = *(const bf16x8*)(vsT + (wv*16 + fr)*72 + k0 + q4*8);
        #pragma unroll
        for (int nt = 0; nt < 4; ++nt) {
            bf16x8 bk = *(const bf16x8*)(kTd + (nt*16 + fr)*72 + k0 + q4*8);
            acc[nt] = __builtin_amdgcn_mfma_f32_16x16x32_bf16(av, bk, acc[nt], 0, 0, 0);
        }
    }

    // z row via ones-A MFMA (wave 0 only)
    if (wv == 0) {
        u16x8 onesu;
        #pragma unroll
        for (int i = 0; i < 8; ++i) onesu[i] = 0x3F80;   // bf16 1.0
        const bf16x8 ones = *(const bf16x8*)&onesu;
        f32x4 zacc[4];
        #pragma unroll
        for (int nt = 0; nt < 4; ++nt) zacc[nt] = (f32x4){0.f,0.f,0.f,0.f};
        #pragma unroll
        for (int k0 = 0; k0 < 64; k0 += 32) {
            #pragma unroll
            for (int nt = 0; nt < 4; ++nt) {
                bf16x8 bk = *(const bf16x8*)(kTd + (nt*16 + fr)*72 + k0 + q4*8);
                zacc[nt] = __builtin_amdgcn_mfma_f32_16x16x32_bf16(ones, bk, zacc[nt], 0, 0, 0);
            }
        }
        if (q4 == 0) {
            #pragma unroll
            for (int nt = 0; nt < 4; ++nt)
                zchunk[slot*64 + nt*16 + fr] = zacc[nt][0];
        }
    }

    // ScT epilogue: C[m=e][n=d], col=fr within tile, row=q4*4+r
    float* sp = Schunk + slot * 4096;
    #pragma unroll
    for (int nt = 0; nt < 4; ++nt) {
        #pragma unroll
        for (int r = 0; r < 4; ++r) {
            const int e = wv*16 + q4*4 + r;
            sp[e*64 + nt*16 + fr] = acc[nt][r];
        }
    }
}

// ---------------------------------------------------------------------------
// Pass 2: sequential over 32 chunks per (bh); elementwise on S^T layout;
// in-place replace contributions with the state ENTERING the chunk.
// ---------------------------------------------------------------------------
__global__ __launch_bounds__(256) void pass2_kernel(
    float* __restrict__ Schunk, float* __restrict__ zchunk,
    const float* __restrict__ Dchunk)
{
    const int bh = blockIdx.x;
    const int tid = threadIdx.x;

    float Sprev[16];
    #pragma unroll
    for (int i = 0; i < 16; ++i) Sprev[i] = 0.f;
    float zprev = 0.f;

    const size_t base  = (size_t)bh * NCHUNK * 4096;
    const size_t zbase = (size_t)bh * NCHUNK * 64;

    for (int c = 0; c < NCHUNK; ++c) {
        const float D = Dchunk[bh * NCHUNK + c];
        float* sp = Schunk + base + (size_t)c * 4096;
        float contrib[16];
        #pragma unroll
        for (int i = 0; i < 16; ++i) contrib[i] = sp[i*256 + tid];
        #pragma unroll
        for (int i = 0; i < 16; ++i) {
            sp[i*256 + tid] = Sprev[i];
            Sprev[i] = D * Sprev[i] + contrib[i];
        }
        if (tid < 64) {
            float* zp = zchunk + zbase + (size_t)c * 64;
            const float zc = zp[tid];
            zp[tid] = zprev;
            zprev = D * zprev + zc;
        }
    }
}

// ---------------------------------------------------------------------------
// Pass 3 (full-MFMA): per (bh, chunk) attention outputs -> bf16 AO.
// ---------------------------------------------------------------------------
__global__ __launch_bounds__(256) void pass3_kernel(
    const ushort_t* __restrict__ Qp, const ushort_t* __restrict__ Kp,
    const ushort_t* __restrict__ VTp, const float* __restrict__ logf,
    const float* __restrict__ S0, const float* __restrict__ z0,
    ushort_t* __restrict__ AO)
{
    __shared__ __align__(16) char smem[28672];
    ushort_t* qs  = (ushort_t*)smem;               // [64][72] bf16 (t rows)
    ushort_t* ks  = (ushort_t*)(smem + 9216);      // [64][72] bf16 (j rows) phase A
    ushort_t* vsT = (ushort_t*)(smem + 9216);      // [64][72] bf16 (e rows) phase B — aliases ks
    ushort_t* psA = (ushort_t*)(smem + 18432);     // [64][72] bf16 P
    float* cc  = (float*)(smem + 27648);
    float* exT = (float*)(smem + 27904);
    float* qz  = (float*)(smem + 28160);
    float* den = (float*)(smem + 28416);

    const int chunk = blockIdx.x;
    const int bh = blockIdx.y;
    const int b = bh >> 4, h = bh & 15;
    const int tid = threadIdx.x;
    const int wv = tid >> 6, ln = tid & 63;
    const int fr = ln & 15, q4 = ln >> 4;
    const size_t slot = (size_t)bh * NCHUNK + chunk;

    if (tid < 64) {
        float v = logf[(size_t)((chunk*64 + tid)*BATCH + b) * HEADS + h];
        #pragma unroll
        for (int off = 1; off < 64; off <<= 1) {
            float n = __shfl_up(v, off);
            if (tid >= off) v += n;
        }
        cc[tid]  = v;
        exT[tid] = __expf(v);
    }
    #pragma unroll
    for (int it = 0; it < 2; ++it) {
        const int u = it*256 + tid;
        const int r = u >> 3, c8 = (u & 7) * 8;
        const size_t goff = (size_t)((chunk*64 + r)*BATCH + b) * HID + h*HD + c8;
        *(u16x8*)(qs + r*72 + c8) = *(const u16x8*)(Qp + goff);
        *(u16x8*)(ks + r*72 + c8) = *(const u16x8*)(Kp + goff);
    }
    __syncthreads();   // B1

    f32x4 pacc[4];
    #pragma unroll
    for (int nt = 0; nt < 4; ++nt) pacc[nt] = (f32x4){0.f,0.f,0.f,0.f};
    #pragma unroll
    for (int k0 = 0; k0 < 64; k0 += 32) {
        bf16x8 af = *(const bf16x8*)(qs + (wv*16 + fr)*72 + k0 + q4*8);
        #pragma unroll
        for (int nt = 0; nt < 4; ++nt) {
            bf16x8 bfr = *(const bf16x8*)(ks + (nt*16 + fr)*72 + k0 + q4*8);
            pacc[nt] = __builtin_amdgcn_mfma_f32_16x16x32_bf16(af, bfr, pacc[nt], 0, 0, 0);
        }
    }
    if (tid < 64) {
        float zown = z0[slot * 64 + tid];
        float s = 0.f;
        for (int d = 0; d < 64; ++d) {
            const float zd = __shfl(zown, d);
            s += bf2f(qs[tid*72 + d]) * zd;
        }
        qz[tid] = s;
    }
    __syncthreads();   // B2

    #pragma unroll
    for (int it = 0; it < 2; ++it) {
        const int u = it*256 + tid;
        const int e = u >> 3, j8 = (u & 7) * 8;
        *(u16x8*)(vsT + e*72 + j8) =
            *(const u16x8*)(VTp + (size_t)b*((size_t)HID*S_LEN)
                            + (size_t)(h*HD + e)*S_LEN + chunk*64 + j8);
    }
    {
        float rs[4] = {0.f, 0.f, 0.f, 0.f};
        float cct[4];
        #pragma unroll
        for (int r = 0; r < 4; ++r) cct[r] = cc[wv*16 + q4*4 + r];
        #pragma unroll
        for (int nt = 0; nt < 4; ++nt) {
            const int j = nt*16 + fr;
            const float ccj = cc[j];
            #pragma unroll
            for (int r = 0; r < 4; ++r) {
                const int t = wv*16 + q4*4 + r;
                float p = (j <= t) ? pacc[nt][r] * __expf(cct[r] - ccj) : 0.f;
                rs[r] += p;
                psA[t*72 + j] = f2bf(p);
            }
        }
        #pragma unroll
        for (int m = 1; m < 16; m <<= 1) {
            #pragma unroll
            for (int r = 0; r < 4; ++r) rs[r] += __shfl_xor(rs[r], m);
        }
        if (fr == 0) {
            #pragma unroll
            for (int r = 0; r < 4; ++r) {
                const int t = wv*16 + q4*4 + r;
                den[t] = rs[r] + exT[t] * qz[t] + 1e-6f;
            }
        }
    }
    __syncthreads();   // B3

    f32x4 oacc[4], oacc2[4];
    #pragma unroll
    for (int nt = 0; nt < 4; ++nt) {
        oacc[nt]  = (f32x4){0.f,0.f,0.f,0.f};
        oacc2[nt] = (f32x4){0.f,0.f,0.f,0.f};
    }
    const float* S0p = S0 + slot * 4096;
    #pragma unroll
    for (int k0 = 0; k0 < 64; k0 += 32) {
        const int k8 = k0 + q4*8;
        bf16x8 ap = *(const bf16x8*)(psA + (wv*16 + fr)*72 + k8);
        bf16x8 aq = *(const bf16x8*)(qs  + (wv*16 + fr)*72 + k8);
        #pragma unroll
        for (int nt = 0; nt < 4; ++nt) {
            bf16x8 bv = *(const bf16x8*)(vsT + (nt*16 + fr)*72 + k8);
            oacc[nt] = __builtin_amdgcn_mfma_f32_16x16x32_bf16(ap, bv, oacc[nt], 0, 0, 0);
            f32x4 s0a = *(const f32x4*)(S0p + (nt*16 + fr)*64 + k8);
            f32x4 s0b = *(const f32x4*)(S0p + (nt*16 + fr)*64 + k8 + 4);
            u16x8 sb;
            #pragma unroll
            for (int i = 0; i < 4; ++i) { sb[i] = f2bf(s0a[i]); sb[4+i] = f2bf(s0b[i]); }
            oacc2[nt] = __builtin_amdgcn_mfma_f32_16x16x32_bf16(aq, *(bf16x8*)&sb, oacc2[nt], 0, 0, 0);
        }
    }
    #pragma unroll
    for (int nt = 0; nt < 4; ++nt) {
        const int e = nt*16 + fr;
        #pragma unroll
        for (int r = 0; r < 4; ++r) {
            const int t = wv*16 + q4*4 + r;
            const float v = (oacc[nt][r] + exT[t] * oacc2[nt][r]) / den[t];
            AO[(size_t)((chunk*64 + t)*BATCH + b) * HID + h*HD + e] = f2bf(v);
        }
    }
}

// ---------------------------------------------------------------------------
extern "C" void kernel_launch(void* const* d_in, const int* in_sizes, int n_in,
                              void* d_out, int out_size, void* d_ws, size_t ws_size,
                              hipStream_t stream) {
    const float* X  = (const float*)d_in[0];
    const float* Wq = (const float*)d_in[1];
    const float* bq = (const float*)d_in[2];
    const float* Wk = (const float*)d_in[3];
    const float* bk = (const float*)d_in[4];
    const float* Wv = (const float*)d_in[5];
    const float* bv = (const float*)d_in[6];
    const float* Wf = (const float*)d_in[7];
    const float* bf = (const float*)d_in[8];
    const float* Wo = (const float*)d_in[9];
    const float* bo = (const float*)d_in[10];

    float* out = (float*)d_out;
    const size_t OUT_SLOT = (size_t)SB * HID;

    char* ws = (char*)d_ws;
    ushort_t* wsXb   = (ushort_t*)ws;                       // SB*HID bf16 (X, later AO)
    ushort_t* wsWstk = wsXb + (size_t)SB * HID;             // NSTK*HID bf16
    ushort_t* wsWob  = wsWstk + (size_t)NSTK * HID;         // HID*HID bf16
    ushort_t* wsQ    = wsWob + (size_t)HID * HID;           // [row][col]
    ushort_t* wsK    = wsQ + (size_t)SB * HID;              // [row][col]
    ushort_t* wsKT   = wsK + (size_t)SB * HID;              // [b][col][s]
    ushort_t* wsVT   = wsKT + (size_t)SB * HID;             // [b][col][s]
    float* wsBstk = (float*)(wsVT + (size_t)SB * HID);      // NSTK fp32
    float* wsLogf = wsBstk + NSTK;                          // SB*HEADS fp32
    float* wsS    = wsLogf + (size_t)SB * HEADS;            // S^T chunks -> S0^T
    float* wsZ    = wsS + (size_t)BH * NCHUNK * HD * HD;
    float* wsD    = wsZ + (size_t)BH * NCHUNK * HD;

    prep_kernel<<<(NTOT + 255)/256, 256, 0, stream>>>(
        X, Wq, Wk, Wv, Wf, Wo, bq, bk, bv, bf,
        wsXb, wsWstk, wsWob, wsBstk);

    dim3 qgrid(NSTK/128, SB/128);   // (25, 64)
    qkvf_gemm<<<qgrid, 256, 0, stream>>>(
        wsXb, wsWstk, wsBstk, wsQ, wsK, wsKT, wsVT,
        out + 2*OUT_SLOT, wsLogf);

    dim3 sgrid(NCHUNK, BH);
    pass1_kernel<<<sgrid, 256, 0, stream>>>(wsKT, wsVT, wsLogf, wsS, wsZ, wsD);
    pass2_kernel<<<BH, 256, 0, stream>>>(wsS, wsZ, wsD);
    pass3_kernel<<<sgrid, 256, 0, stream>>>(wsQ, wsK, wsVT, wsLogf, wsS, wsZ, wsXb);

    dim3 ogrid(HID/128, SB/128);
    gemm_out<<<ogrid, 256, 0, stream>>>(wsXb, wsWob, bo, out, out + OUT_SLOT);
}

// Round 6
// 300.832 us; speedup vs baseline: 5.9715x; 1.0989x over previous
//
#include <hip/hip_runtime.h>
#include <hip/hip_bf16.h>
#include <math.h>

// Problem constants
#define S_LEN 2048
#define BATCH 4
#define HID   1024
#define HEADS 16
#define HD    64
#define SB    (S_LEN*BATCH)       // 8192 rows
#define CHUNK 64
#define NCHUNK (S_LEN/CHUNK)      // 32
#define BH    (BATCH*HEADS)       // 64
#define NSTK  3200                // 1024*3 (QKV) + 16 (F) padded to 25*128

typedef __bf16 bf16x8 __attribute__((ext_vector_type(8)));
typedef float  f32x4  __attribute__((ext_vector_type(4)));
typedef unsigned short ushort_t;
typedef unsigned short u16x8 __attribute__((ext_vector_type(8)));

__device__ __forceinline__ unsigned short f2bf(float x) {
    union { float f; unsigned int u; } un; un.f = x;
    unsigned int u = un.u;
    unsigned int r = (u + 0x7FFFu + ((u >> 16) & 1u)) >> 16;  // RNE
    return (unsigned short)r;
}
__device__ __forceinline__ float bf2f(unsigned short s) {
    union { unsigned int u; float f; } un; un.u = ((unsigned int)s) << 16;
    return un.f;
}

// ---------------------------------------------------------------------------
// Prep kernel (one dispatch): X->bf16; Wstk build; Wo->bf16; bstk build.
// ---------------------------------------------------------------------------
#define NXU (SB*HID/4)          // 2097152
#define NW1 (NSTK*HID/4)        // 819200
#define NW2 (HID*HID/4)         // 262144
#define NBU (NSTK/4)            // 800
#define NTOT (NXU+NW1+NW2+NBU)

__global__ __launch_bounds__(256) void prep_kernel(
    const float* __restrict__ X,  const float* __restrict__ Wq,
    const float* __restrict__ Wk, const float* __restrict__ Wv,
    const float* __restrict__ Wf, const float* __restrict__ Wo,
    const float* __restrict__ bq, const float* __restrict__ bk,
    const float* __restrict__ bv, const float* __restrict__ bf,
    ushort_t* __restrict__ Xb, ushort_t* __restrict__ Wstk,
    ushort_t* __restrict__ Wob, float* __restrict__ bstk)
{
    const int i = blockIdx.x * 256 + threadIdx.x;
    if (i < NXU) {
        float4 v = ((const float4*)X)[i];
        ushort4 o; o.x=f2bf(v.x); o.y=f2bf(v.y); o.z=f2bf(v.z); o.w=f2bf(v.w);
        ((ushort4*)Xb)[i] = o;
    } else if (i < NXU + NW1) {
        const int idx4 = (i - NXU) * 4;
        const int row = idx4 >> 10, col = idx4 & 1023;
        float4 v;
        if      (row < 1024) v = *(const float4*)(Wq + (size_t)row*HID + col);
        else if (row < 2048) v = *(const float4*)(Wk + (size_t)(row-1024)*HID + col);
        else if (row < 3072) v = *(const float4*)(Wv + (size_t)(row-2048)*HID + col);
        else if (row < 3088) v = *(const float4*)(Wf + (size_t)(row-3072)*HID + col);
        else                 v = make_float4(0.f,0.f,0.f,0.f);
        ushort4 o; o.x=f2bf(v.x); o.y=f2bf(v.y); o.z=f2bf(v.z); o.w=f2bf(v.w);
        *(ushort4*)(Wstk + idx4) = o;
    } else if (i < NXU + NW1 + NW2) {
        const int idx4 = (i - NXU - NW1) * 4;
        float4 v = *(const float4*)(Wo + idx4);
        ushort4 o; o.x=f2bf(v.x); o.y=f2bf(v.y); o.z=f2bf(v.z); o.w=f2bf(v.w);
        *(ushort4*)(Wob + idx4) = o;
    } else if (i < NTOT) {
        const int idx4 = (i - NXU - NW1 - NW2) * 4;
        #pragma unroll
        for (int t = 0; t < 4; ++t) {
            const int c = idx4 + t;
            float v;
            if      (c < 1024) v = bq[c];
            else if (c < 2048) v = bk[c-1024];
            else if (c < 3072) v = bv[c-2048];
            else if (c < 3088) v = bf[c-3072];
            else               v = 0.f;
            bstk[c] = v;
        }
    }
}

// ---------------------------------------------------------------------------
// Fused QKV+F GEMM: S = Xb[8192,1024] @ Wstk[3200,1024]^T + bstk.
// Grid: x = ROW panel (64), y = COL panel (25). 64%8==0 -> XCD = row%8 for
// every column: each XCD keeps its 2MB A-slice L2-resident across all cols.
// Epilogue (block-uniform col group): Q/K: elu+1 -> bf16 row-major;
// V: bf16 row-major; F: sigmoid fp32 + logf. NO transposed global writes.
// ---------------------------------------------------------------------------
__global__ __launch_bounds__(256) void qkvf_gemm(
    const ushort_t* __restrict__ X, const ushort_t* __restrict__ W,
    const float* __restrict__ bias,
    ushort_t* __restrict__ Q, ushort_t* __restrict__ Kr,
    ushort_t* __restrict__ V,
    float* __restrict__ f_out, float* __restrict__ logf_out)
{
    __shared__ ushort_t As[128 * 32];
    __shared__ ushort_t Bs[128 * 32];

    const int tid  = threadIdx.x;
    const int wave = tid >> 6, lane = tid & 63;
    const int waveM = wave >> 1, waveN = wave & 1;
    const int rowBase = blockIdx.x * 128;
    const int colBase = blockIdx.y * 128;
    const int K = HID;

    f32x4 acc[4][4];
    #pragma unroll
    for (int i = 0; i < 4; ++i)
        #pragma unroll
        for (int j = 0; j < 4; ++j)
            acc[i][j] = (f32x4){0.f, 0.f, 0.f, 0.f};

    const int srow = lane >> 2;
    const int scol = (lane & 3) * 8;

    const ushort_t* gA0 = X + (size_t)(rowBase + wave*16 + srow) * K + scol;
    const ushort_t* gB0 = W + (size_t)(colBase + wave*16 + srow) * K + scol;
    ushort_t* lA = As + (wave*16)*32;
    ushort_t* lB = Bs + (wave*16)*32;

    const int fr = lane & 15;
    const int fk = (lane >> 4) * 8;

    for (int k0 = 0; k0 < K; k0 += 32) {
        __builtin_amdgcn_global_load_lds(
            (const __attribute__((address_space(1))) void*)(gA0 + k0),
            (__attribute__((address_space(3))) void*)lA, 16, 0, 0);
        __builtin_amdgcn_global_load_lds(
            (const __attribute__((address_space(1))) void*)(gA0 + (size_t)64*K + k0),
            (__attribute__((address_space(3))) void*)(lA + 64*32), 16, 0, 0);
        __builtin_amdgcn_global_load_lds(
            (const __attribute__((address_space(1))) void*)(gB0 + k0),
            (__attribute__((address_space(3))) void*)lB, 16, 0, 0);
        __builtin_amdgcn_global_load_lds(
            (const __attribute__((address_space(1))) void*)(gB0 + (size_t)64*K + k0),
            (__attribute__((address_space(3))) void*)(lB + 64*32), 16, 0, 0);

        __syncthreads();

        bf16x8 a[4], b[4];
        #pragma unroll
        for (int i = 0; i < 4; ++i)
            a[i] = *(const bf16x8*)(As + (waveM*64 + i*16 + fr)*32 + fk);
        #pragma unroll
        for (int j = 0; j < 4; ++j)
            b[j] = *(const bf16x8*)(Bs + (waveN*64 + j*16 + fr)*32 + fk);

        #pragma unroll
        for (int i = 0; i < 4; ++i)
            #pragma unroll
            for (int j = 0; j < 4; ++j)
                acc[i][j] = __builtin_amdgcn_mfma_f32_16x16x32_bf16(
                    a[i], b[j], acc[i][j], 0, 0, 0);

        __syncthreads();
    }

    const int er = (lane >> 4) * 4;
    const int ec = lane & 15;
    #pragma unroll
    for (int i = 0; i < 4; ++i) {
        #pragma unroll
        for (int j = 0; j < 4; ++j) {
            const int r0 = rowBase + waveM*64 + i*16 + er;
            const int c0 = colBase + waveN*64 + j*16;        // lane-uniform
            if (c0 >= 3088) continue;
            const int c  = c0 + ec;
            const float bv = bias[c];
            #pragma unroll
            for (int k = 0; k < 4; ++k) {
                float v = acc[i][j][k] + bv;
                const int r = r0 + k;
                if (c0 < 1024) {
                    v = (v > 0.f) ? (v + 1.f) : __expf(v);
                    Q[(size_t)r * HID + c] = f2bf(v);
                } else if (c0 < 2048) {
                    v = (v > 0.f) ? (v + 1.f) : __expf(v);
                    Kr[(size_t)r * HID + (c - 1024)] = f2bf(v);
                } else if (c0 < 3072) {
                    V[(size_t)r * HID + (c - 2048)] = f2bf(v);
                } else {
                    const int n = c - 3072;
                    const float fv = 1.f / (1.f + __expf(-v));
                    f_out[(size_t)r * HEADS + n]    = fv;
                    logf_out[(size_t)r * HEADS + n] = -__logf(1.f + __expf(-v));
                }
            }
        }
    }
}

// ---------------------------------------------------------------------------
// Output GEMM: out = AO @ Wo^T + bo (fp32) + fused zero-fill of slot 1.
// Grid x = ROW panel (64), y = COL panel (8) for the same XCD/L2 locality.
// ---------------------------------------------------------------------------
__global__ __launch_bounds__(256) void gemm_out(
    const ushort_t* __restrict__ X, const ushort_t* __restrict__ W,
    const float* __restrict__ bias, float* __restrict__ Y,
    float* __restrict__ Yzero)
{
    __shared__ ushort_t As[128 * 32];
    __shared__ ushort_t Bs[128 * 32];

    const int tid  = threadIdx.x;
    const int wave = tid >> 6, lane = tid & 63;
    const int waveM = wave >> 1, waveN = wave & 1;
    const int rowBase = blockIdx.x * 128;
    const int colBase = blockIdx.y * 128;
    const int K = HID, N = HID;

    f32x4 acc[4][4];
    #pragma unroll
    for (int i = 0; i < 4; ++i)
        #pragma unroll
        for (int j = 0; j < 4; ++j)
            acc[i][j] = (f32x4){0.f, 0.f, 0.f, 0.f};

    const int srow = lane >> 2;
    const int scol = (lane & 3) * 8;

    const ushort_t* gA0 = X + (size_t)(rowBase + wave*16 + srow) * K + scol;
    const ushort_t* gB0 = W + (size_t)(colBase + wave*16 + srow) * K + scol;
    ushort_t* lA = As + (wave*16)*32;
    ushort_t* lB = Bs + (wave*16)*32;

    const int fr = lane & 15;
    const int fk = (lane >> 4) * 8;

    for (int k0 = 0; k0 < K; k0 += 32) {
        __builtin_amdgcn_global_load_lds(
            (const __attribute__((address_space(1))) void*)(gA0 + k0),
            (__attribute__((address_space(3))) void*)lA, 16, 0, 0);
        __builtin_amdgcn_global_load_lds(
            (const __attribute__((address_space(1))) void*)(gA0 + (size_t)64*K + k0),
            (__attribute__((address_space(3))) void*)(lA + 64*32), 16, 0, 0);
        __builtin_amdgcn_global_load_lds(
            (const __attribute__((address_space(1))) void*)(gB0 + k0),
            (__attribute__((address_space(3))) void*)lB, 16, 0, 0);
        __builtin_amdgcn_global_load_lds(
            (const __attribute__((address_space(1))) void*)(gB0 + (size_t)64*K + k0),
            (__attribute__((address_space(3))) void*)(lB + 64*32), 16, 0, 0);

        __syncthreads();

        bf16x8 a[4], b[4];
        #pragma unroll
        for (int i = 0; i < 4; ++i)
            a[i] = *(const bf16x8*)(As + (waveM*64 + i*16 + fr)*32 + fk);
        #pragma unroll
        for (int j = 0; j < 4; ++j)
            b[j] = *(const bf16x8*)(Bs + (waveN*64 + j*16 + fr)*32 + fk);

        #pragma unroll
        for (int i = 0; i < 4; ++i)
            #pragma unroll
            for (int j = 0; j < 4; ++j)
                acc[i][j] = __builtin_amdgcn_mfma_f32_16x16x32_bf16(
                    a[i], b[j], acc[i][j], 0, 0, 0);

        __syncthreads();
    }

    const int er = (lane >> 4) * 4;
    const int ec = lane & 15;
    #pragma unroll
    for (int i = 0; i < 4; ++i) {
        #pragma unroll
        for (int j = 0; j < 4; ++j) {
            const int r0 = rowBase + waveM*64 + i*16 + er;
            const int c  = colBase + waveN*64 + j*16 + ec;
            const float bv = bias[c];
            #pragma unroll
            for (int k = 0; k < 4; ++k) {
                const size_t off = (size_t)(r0 + k) * N + c;
                Y[off] = acc[i][j][k] + bv;
                Yzero[off] = 0.f;
            }
        }
    }
}

// ---------------------------------------------------------------------------
// Pass 1 (MFMA): per (bh, chunk):
//   ScT[e][d] = sum_j v[j][e] * (exd_j k[j][d]);  z[d] = sum_j exd_j k[j][d]
// K,V read ROW-MAJOR (coalesced); j-major LDS tiles built by consumer-side
// transpose (8x ds_write_b16 scatter per u16x8).
// ---------------------------------------------------------------------------
__global__ __launch_bounds__(256) void pass1_kernel(
    const ushort_t* __restrict__ Kp, const ushort_t* __restrict__ Vp,
    const float* __restrict__ logf,
    float* __restrict__ Schunk, float* __restrict__ zchunk,
    float* __restrict__ Dchunk)
{
    __shared__ __align__(16) char smem[18688];
    ushort_t* vsT = (ushort_t*)smem;            // [64][72]: row e, col j
    ushort_t* kTd = (ushort_t*)(smem + 9216);   // [64][72]: row d, col j (decayed)
    float*    exd = (float*)(smem + 18432);     // [64]

    const int chunk = blockIdx.x;
    const int bh = blockIdx.y;
    const int b = bh >> 4, h = bh & 15;
    const int tid = threadIdx.x;
    const int wv = tid >> 6, ln = tid & 63;
    const int fr = ln & 15, q4 = ln >> 4;
    const size_t slot = (size_t)bh * NCHUNK + chunk;

    // register-preload (row-major, coalesced) — overlaps wave0 scan
    u16x8 vreg[2], kreg[2];
    #pragma unroll
    for (int it = 0; it < 2; ++it) {
        const int u = it*256 + tid;
        const int j = u >> 3, d8 = (u & 7) * 8;
        const size_t base = (size_t)((chunk*64 + j)*BATCH + b)*HID + h*HD + d8;
        vreg[it] = *(const u16x8*)(Vp + base);
        kreg[it] = *(const u16x8*)(Kp + base);
    }
    if (tid < 64) {
        float v = logf[(size_t)((chunk*64 + tid)*BATCH + b) * HEADS + h];
        #pragma unroll
        for (int off = 1; off < 64; off <<= 1) {
            float n = __shfl_up(v, off);
            if (tid >= off) v += n;
        }
        const float tot = __shfl(v, 63);
        exd[tid] = __expf(tot - v);
        if (tid == 63) Dchunk[slot] = __expf(tot);
    }
    __syncthreads();

    #pragma unroll
    for (int it = 0; it < 2; ++it) {
        const int u = it*256 + tid;
        const int j = u >> 3, d8 = (u & 7) * 8;
        const float ex = exd[j];
        #pragma unroll
        for (int i = 0; i < 8; ++i) {
            vsT[(d8+i)*72 + j] = vreg[it][i];
            kTd[(d8+i)*72 + j] = f2bf(bf2f(kreg[it][i]) * ex);
        }
    }
    __syncthreads();

    f32x4 acc[4];
    #pragma unroll
    for (int nt = 0; nt < 4; ++nt) acc[nt] = (f32x4){0.f,0.f,0.f,0.f};
    #pragma unroll
    for (int k0 = 0; k0 < 64; k0 += 32) {
        bf16x8 av = *(const bf16x8*)(vsT + (wv*16 + fr)*72 + k0 + q4*8);
        #pragma unroll
        for (int nt = 0; nt < 4; ++nt) {
            bf16x8 bk = *(const bf16x8*)(kTd + (nt*16 + fr)*72 + k0 + q4*8);
            acc[nt] = __builtin_amdgcn_mfma_f32_16x16x32_bf16(av, bk, acc[nt], 0, 0, 0);
        }
    }

    // z row via ones-A MFMA (wave 0 only)
    if (wv == 0) {
        u16x8 onesu;
        #pragma unroll
        for (int i = 0; i < 8; ++i) onesu[i] = 0x3F80;   // bf16 1.0
        const bf16x8 ones = *(const bf16x8*)&onesu;
        f32x4 zacc[4];
        #pragma unroll
        for (int nt = 0; nt < 4; ++nt) zacc[nt] = (f32x4){0.f,0.f,0.f,0.f};
        #pragma unroll
        for (int k0 = 0; k0 < 64; k0 += 32) {
            #pragma unroll
            for (int nt = 0; nt < 4; ++nt) {
                bf16x8 bk = *(const bf16x8*)(kTd + (nt*16 + fr)*72 + k0 + q4*8);
                zacc[nt] = __builtin_amdgcn_mfma_f32_16x16x32_bf16(ones, bk, zacc[nt], 0, 0, 0);
            }
        }
        if (q4 == 0) {
            #pragma unroll
            for (int nt = 0; nt < 4; ++nt)
                zchunk[slot*64 + nt*16 + fr] = zacc[nt][0];
        }
    }

    float* sp = Schunk + slot * 4096;
    #pragma unroll
    for (int nt = 0; nt < 4; ++nt) {
        #pragma unroll
        for (int r = 0; r < 4; ++r) {
            const int e = wv*16 + q4*4 + r;
            sp[e*64 + nt*16 + fr] = acc[nt][r];
        }
    }
}

// ---------------------------------------------------------------------------
// Pass 2: sequential over 32 chunks per (bh); elementwise on S^T layout.
// ---------------------------------------------------------------------------
__global__ __launch_bounds__(256) void pass2_kernel(
    float* __restrict__ Schunk, float* __restrict__ zchunk,
    const float* __restrict__ Dchunk)
{
    const int bh = blockIdx.x;
    const int tid = threadIdx.x;

    float Sprev[16];
    #pragma unroll
    for (int i = 0; i < 16; ++i) Sprev[i] = 0.f;
    float zprev = 0.f;

    const size_t base  = (size_t)bh * NCHUNK * 4096;
    const size_t zbase = (size_t)bh * NCHUNK * 64;

    for (int c = 0; c < NCHUNK; ++c) {
        const float D = Dchunk[bh * NCHUNK + c];
        float* sp = Schunk + base + (size_t)c * 4096;
        float contrib[16];
        #pragma unroll
        for (int i = 0; i < 16; ++i) contrib[i] = sp[i*256 + tid];
        #pragma unroll
        for (int i = 0; i < 16; ++i) {
            sp[i*256 + tid] = Sprev[i];
            Sprev[i] = D * Sprev[i] + contrib[i];
        }
        if (tid < 64) {
            float* zp = zchunk + zbase + (size_t)c * 64;
            const float zc = zp[tid];
            zp[tid] = zprev;
            zprev = D * zprev + zc;
        }
    }
}

// ---------------------------------------------------------------------------
// Pass 3 (full-MFMA): per (bh, chunk) attention outputs -> bf16 AO.
// V staged via consumer-side transpose from row-major V.
// ---------------------------------------------------------------------------
__global__ __launch_bounds__(256) void pass3_kernel(
    const ushort_t* __restrict__ Qp, const ushort_t* __restrict__ Kp,
    const ushort_t* __restrict__ Vp, const float* __restrict__ logf,
    const float* __restrict__ S0, const float* __restrict__ z0,
    ushort_t* __restrict__ AO)
{
    __shared__ __align__(16) char smem[28672];
    ushort_t* qs  = (ushort_t*)smem;               // [64][72] (t rows)
    ushort_t* ks  = (ushort_t*)(smem + 9216);      // [64][72] (j rows) phase A
    ushort_t* vsT = (ushort_t*)(smem + 9216);      // [64][72] (e rows, j cols) phase B
    ushort_t* psA = (ushort_t*)(smem + 18432);     // [64][72] P
    float* cc  = (float*)(smem + 27648);
    float* exT = (float*)(smem + 27904);
    float* qz  = (float*)(smem + 28160);
    float* den = (float*)(smem + 28416);

    const int chunk = blockIdx.x;
    const int bh = blockIdx.y;
    const int b = bh >> 4, h = bh & 15;
    const int tid = threadIdx.x;
    const int wv = tid >> 6, ln = tid & 63;
    const int fr = ln & 15, q4 = ln >> 4;
    const size_t slot = (size_t)bh * NCHUNK + chunk;

    // prefetch V rows into registers (scattered to LDS after B2)
    u16x8 vreg[2];
    #pragma unroll
    for (int it = 0; it < 2; ++it) {
        const int u = it*256 + tid;
        const int j = u >> 3, d8 = (u & 7) * 8;
        vreg[it] = *(const u16x8*)(Vp + (size_t)((chunk*64 + j)*BATCH + b)*HID + h*HD + d8);
    }

    if (tid < 64) {
        float v = logf[(size_t)((chunk*64 + tid)*BATCH + b) * HEADS + h];
        #pragma unroll
        for (int off = 1; off < 64; off <<= 1) {
            float n = __shfl_up(v, off);
            if (tid >= off) v += n;
        }
        cc[tid]  = v;
        exT[tid] = __expf(v);
    }
    #pragma unroll
    for (int it = 0; it < 2; ++it) {
        const int u = it*256 + tid;
        const int r = u >> 3, c8 = (u & 7) * 8;
        const size_t goff = (size_t)((chunk*64 + r)*BATCH + b) * HID + h*HD + c8;
        *(u16x8*)(qs + r*72 + c8) = *(const u16x8*)(Qp + goff);
        *(u16x8*)(ks + r*72 + c8) = *(const u16x8*)(Kp + goff);
    }
    __syncthreads();   // B1

    f32x4 pacc[4];
    #pragma unroll
    for (int nt = 0; nt < 4; ++nt) pacc[nt] = (f32x4){0.f,0.f,0.f,0.f};
    #pragma unroll
    for (int k0 = 0; k0 < 64; k0 += 32) {
        bf16x8 af = *(const bf16x8*)(qs + (wv*16 + fr)*72 + k0 + q4*8);
        #pragma unroll
        for (int nt = 0; nt < 4; ++nt) {
            bf16x8 bfr = *(const bf16x8*)(ks + (nt*16 + fr)*72 + k0 + q4*8);
            pacc[nt] = __builtin_amdgcn_mfma_f32_16x16x32_bf16(af, bfr, pacc[nt], 0, 0, 0);
        }
    }
    if (tid < 64) {
        float zown = z0[slot * 64 + tid];
        float s = 0.f;
        for (int d = 0; d < 64; ++d) {
            const float zd = __shfl(zown, d);
            s += bf2f(qs[tid*72 + d]) * zd;
        }
        qz[tid] = s;
    }
    __syncthreads();   // B2 — ks reads done; vsT may overwrite

    #pragma unroll
    for (int it = 0; it < 2; ++it) {
        const int u = it*256 + tid;
        const int j = u >> 3, d8 = (u & 7) * 8;
        #pragma unroll
        for (int i = 0; i < 8; ++i)
            vsT[(d8+i)*72 + j] = vreg[it][i];
    }
    {
        float rs[4] = {0.f, 0.f, 0.f, 0.f};
        float cct[4];
        #pragma unroll
        for (int r = 0; r < 4; ++r) cct[r] = cc[wv*16 + q4*4 + r];
        #pragma unroll
        for (int nt = 0; nt < 4; ++nt) {
            const int j = nt*16 + fr;
            const float ccj = cc[j];
            #pragma unroll
            for (int r = 0; r < 4; ++r) {
                const int t = wv*16 + q4*4 + r;
                float p = (j <= t) ? pacc[nt][r] * __expf(cct[r] - ccj) : 0.f;
                rs[r] += p;
                psA[t*72 + j] = f2bf(p);
            }
        }
        #pragma unroll
        for (int m = 1; m < 16; m <<= 1) {
            #pragma unroll
            for (int r = 0; r < 4; ++r) rs[r] += __shfl_xor(rs[r], m);
        }
        if (fr == 0) {
            #pragma unroll
            for (int r = 0; r < 4; ++r) {
                const int t = wv*16 + q4*4 + r;
                den[t] = rs[r] + exT[t] * qz[t] + 1e-6f;
            }
        }
    }
    __syncthreads();   // B3

    f32x4 oacc[4], oacc2[4];
    #pragma unroll
    for (int nt = 0; nt < 4; ++nt) {
        oacc[nt]  = (f32x4){0.f,0.f,0.f,0.f};
        oacc2[nt] = (f32x4){0.f,0.f,0.f,0.f};
    }
    const float* S0p = S0 + slot * 4096;
    #pragma unroll
    for (int k0 = 0; k0 < 64; k0 += 32) {
        const int k8 = k0 + q4*8;
        bf16x8 ap = *(const bf16x8*)(psA + (wv*16 + fr)*72 + k8);
        bf16x8 aq = *(const bf16x8*)(qs  + (wv*16 + fr)*72 + k8);
        #pragma unroll
        for (int nt = 0; nt < 4; ++nt) {
            bf16x8 bv = *(const bf16x8*)(vsT + (nt*16 + fr)*72 + k8);
            oacc[nt] = __builtin_amdgcn_mfma_f32_16x16x32_bf16(ap, bv, oacc[nt], 0, 0, 0);
            f32x4 s0a = *(const f32x4*)(S0p + (nt*16 + fr)*64 + k8);
            f32x4 s0b = *(const f32x4*)(S0p + (nt*16 + fr)*64 + k8 + 4);
            u16x8 sb;
            #pragma unroll
            for (int i = 0; i < 4; ++i) { sb[i] = f2bf(s0a[i]); sb[4+i] = f2bf(s0b[i]); }
            oacc2[nt] = __builtin_amdgcn_mfma_f32_16x16x32_bf16(aq, *(bf16x8*)&sb, oacc2[nt], 0, 0, 0);
        }
    }
    #pragma unroll
    for (int nt = 0; nt < 4; ++nt) {
        const int e = nt*16 + fr;
        #pragma unroll
        for (int r = 0; r < 4; ++r) {
            const int t = wv*16 + q4*4 + r;
            const float v = (oacc[nt][r] + exT[t] * oacc2[nt][r]) / den[t];
            AO[(size_t)((chunk*64 + t)*BATCH + b) * HID + h*HD + e] = f2bf(v);
        }
    }
}

// ---------------------------------------------------------------------------
extern "C" void kernel_launch(void* const* d_in, const int* in_sizes, int n_in,
                              void* d_out, int out_size, void* d_ws, size_t ws_size,
                              hipStream_t stream) {
    const float* X  = (const float*)d_in[0];
    const float* Wq = (const float*)d_in[1];
    const float* bq = (const float*)d_in[2];
    const float* Wk = (const float*)d_in[3];
    const float* bk = (const float*)d_in[4];
    const float* Wv = (const float*)d_in[5];
    const float* bv = (const float*)d_in[6];
    const float* Wf = (const float*)d_in[7];
    const float* bf = (const float*)d_in[8];
    const float* Wo = (const float*)d_in[9];
    const float* bo = (const float*)d_in[10];

    float* out = (float*)d_out;
    const size_t OUT_SLOT = (size_t)SB * HID;

    char* ws = (char*)d_ws;
    ushort_t* wsXb   = (ushort_t*)ws;                       // SB*HID bf16 (X, later AO)
    ushort_t* wsWstk = wsXb + (size_t)SB * HID;             // NSTK*HID bf16
    ushort_t* wsWob  = wsWstk + (size_t)NSTK * HID;         // HID*HID bf16
    ushort_t* wsQ    = wsWob + (size_t)HID * HID;           // [row][col]
    ushort_t* wsK    = wsQ + (size_t)SB * HID;              // [row][col]
    ushort_t* wsV    = wsK + (size_t)SB * HID;              // [row][col]
    float* wsBstk = (float*)(wsV + (size_t)SB * HID);       // NSTK fp32
    float* wsLogf = wsBstk + NSTK;                          // SB*HEADS fp32
    float* wsS    = wsLogf + (size_t)SB * HEADS;            // S^T chunks -> S0^T
    float* wsZ    = wsS + (size_t)BH * NCHUNK * HD * HD;
    float* wsD    = wsZ + (size_t)BH * NCHUNK * HD;

    prep_kernel<<<(NTOT + 255)/256, 256, 0, stream>>>(
        X, Wq, Wk, Wv, Wf, Wo, bq, bk, bv, bf,
        wsXb, wsWstk, wsWob, wsBstk);

    dim3 qgrid(SB/128, NSTK/128);   // x = row (64), y = col (25)
    qkvf_gemm<<<qgrid, 256, 0, stream>>>(
        wsXb, wsWstk, wsBstk, wsQ, wsK, wsV,
        out + 2*OUT_SLOT, wsLogf);

    dim3 sgrid(NCHUNK, BH);
    pass1_kernel<<<sgrid, 256, 0, stream>>>(wsK, wsV, wsLogf, wsS, wsZ, wsD);
    pass2_kernel<<<BH, 256, 0, stream>>>(wsS, wsZ, wsD);
    pass3_kernel<<<sgrid, 256, 0, stream>>>(wsQ, wsK, wsV, wsLogf, wsS, wsZ, wsXb);

    dim3 ogrid(SB/128, HID/128);    // x = row (64), y = col (8)
    gemm_out<<<ogrid, 256, 0, stream>>>(wsXb, wsWob, bo, out, out + OUT_SLOT);
}